// Round 13
// baseline (4593.387 us; speedup 1.0000x reference)
//
#include <hip/hip_runtime.h>
#include <hip/hip_bf16.h>

#define B_ 128
#define T_ 1024
#define E_ 32
#define H_ 100
#define C_ 20
#define M_ (B_*T_)   // 131072

typedef __attribute__((ext_vector_type(8))) short bf16x8v;
typedef __attribute__((ext_vector_type(4))) float f32x4v;
typedef unsigned short u16;

static __device__ __forceinline__ short f2b(float x) {
  union { __hip_bfloat16 b; short s; } u;
  u.b = __float2bfloat16(x);
  return u.s;
}
static __device__ __forceinline__ float b2f(u16 x) {
  return __uint_as_float(((unsigned int)x) << 16);
}

// ---------------- embedding lookup ----------------
__global__ void embed_k(const int* __restrict__ tok, const float* __restrict__ emb,
                        float* __restrict__ x0) {
  int idx = blockIdx.x * 256 + threadIdx.x;   // over M_*E_ = 4194304
  int bt = idx >> 5;
  int e  = idx & 31;
  x0[idx] = emb[tok[bt] * E_ + e];
}

// ---------------- bf16 MFMA GEMM: C[M,N] = A[M,K] @ W[N,K]^T + b1 + b2 ------
template<int ABF, int OBF>
__global__ __launch_bounds__(256) void gemm_mfma_t(
    const void* __restrict__ Av, const float* __restrict__ W,
    const float* __restrict__ b1, const float* __restrict__ b2,
    void* __restrict__ Cv, int K, int N, int ldc)
{
  __shared__ short as[64 * 40];   // [row][k] pad 40
  __shared__ short ws[64 * 40];   // [col][k]
  const float* Af = (const float*)Av;
  const u16*   Ab = (const u16*)Av;
  float* Cf = (float*)Cv;
  u16*   Cb = (u16*)Cv;
  int tid = threadIdx.x, lane = tid & 63, w = tid >> 6;
  int lr = lane & 15, lq = lane >> 4;
  size_t m0 = (size_t)blockIdx.x * 64;
  int n0 = blockIdx.y * 64;
  int srow = tid >> 2;            // staging row 0..63
  int sk = (tid & 3) * 8;         // staging k offset 0,8,16,24
  bool wok = (n0 + srow) < N;
  const float* Wp = wok ? (W + (size_t)(n0 + srow) * K + sk) : W;
  size_t arow = (m0 + srow) * (size_t)K;
  f32x4v acc[4];
  #pragma unroll
  for (int r = 0; r < 4; ++r) acc[r] = (f32x4v){0.f, 0.f, 0.f, 0.f};
  int ksteps = (K + 31) / 32;
  for (int ks = 0; ks < ksteps; ++ks) {
    int kk = ks * 32;
    bf16x8v av, wv;
    if (kk + sk + 7 < K) {
      if (ABF) {
        av = *(const bf16x8v*)(Ab + arow + kk + sk);
      } else {
        float4 a0 = *(const float4*)(Af + arow + kk + sk);
        float4 a1 = *(const float4*)(Af + arow + kk + sk + 4);
        av[0]=f2b(a0.x); av[1]=f2b(a0.y); av[2]=f2b(a0.z); av[3]=f2b(a0.w);
        av[4]=f2b(a1.x); av[5]=f2b(a1.y); av[6]=f2b(a1.z); av[7]=f2b(a1.w);
      }
      if (wok) {
        float4 w0 = *(const float4*)(Wp + kk);
        float4 w1 = *(const float4*)(Wp + kk + 4);
        wv[0]=f2b(w0.x); wv[1]=f2b(w0.y); wv[2]=f2b(w0.z); wv[3]=f2b(w0.w);
        wv[4]=f2b(w1.x); wv[5]=f2b(w1.y); wv[6]=f2b(w1.z); wv[7]=f2b(w1.w);
      } else {
        #pragma unroll
        for (int j = 0; j < 8; ++j) wv[j] = 0;
      }
    } else {
      #pragma unroll
      for (int j = 0; j < 8; ++j) {
        int k = kk + sk + j;
        av[j] = (k < K) ? (ABF ? (short)Ab[arow + k] : f2b(Af[arow + k])) : (short)0;
        wv[j] = (wok && k < K) ? f2b(W[(size_t)(n0 + srow) * K + k]) : (short)0;
      }
    }
    *(bf16x8v*)&as[srow * 40 + sk] = av;
    *(bf16x8v*)&ws[srow * 40 + sk] = wv;
    __syncthreads();
    bf16x8v bf = *(const bf16x8v*)&ws[(16 * w + lr) * 40 + 8 * lq];
    #pragma unroll
    for (int r = 0; r < 4; ++r) {
      bf16x8v af = *(const bf16x8v*)&as[(16 * r + lr) * 40 + 8 * lq];
      acc[r] = __builtin_amdgcn_mfma_f32_16x16x32_bf16(af, bf, acc[r], 0, 0, 0);
    }
    __syncthreads();
  }
  int col = n0 + 16 * w + lr;
  if (col < N) {
    float bv = (b1 ? b1[col] : 0.f) + (b2 ? b2[col] : 0.f);
    #pragma unroll
    for (int r = 0; r < 4; ++r)
      #pragma unroll
      for (int rg = 0; rg < 4; ++rg) {
        size_t off = (m0 + 16 * r + 4 * lq + rg) * (size_t)ldc + col;
        float v = acc[r][rg] + bv;
        if (OBF) Cb[off] = (u16)f2b(v); else Cf[off] = v;
      }
  }
}

// Pin a float4's components into VGPRs (blocks rematerialization of the load).
#define PIN4(v) asm volatile("" : "+v"((v).x), "+v"((v).y), "+v"((v).z), "+v"((v).w))

// ---------------- LSTM scan, hybrid reg/LDS weights -----------------
// r12 post-mortem: at 256thr the RA reliably allocates 128-132 VGPR (r6,r12)
// but demand was 230 -> ~100 f32/thread scratch-spilled per step (960us).
// Fix: size register demand to the PROVEN ceiling. Thread tid<200 owns rows
// 2tid (fp32 REGISTERS: 25xfloat4 = 100 VGPR, demand ~125 <= 128) and 2tid+1
// (LDS: woddT[50][200] float2 column-major -> consecutive lanes read
// consecutive float2 = conflict-free ds_read_b64; 80KB/step ~ 625cy port).
// h read as 25 UNIFORM-address b128 broadcasts (r8 proved broadcast is cheap;
// replaces r4's 100 readlanes). Static LDS ~82KB (r8 precedent: 160KB ok)
// -> 1 WG/CU. xp read bf16, h written bf16 (r12 win).
__global__ __launch_bounds__(256, 1) void lstm_scan(
    const u16* __restrict__ xp,
    const float* __restrict__ WhhF, const float* __restrict__ WhhR,
    const float* __restrict__ h0, const float* __restrict__ c0, // [4][B][H]
    const int* __restrict__ seqlen,   // null => no mask
    u16* __restrict__ outbuf,         // [B][T][200] bf16, dir*100 offset
    int layer)
{
  int wg = blockIdx.x; int dir = wg & 1; int b = wg >> 1;
  int tid = threadIdx.x;
  const float* Whh = dir ? WhhR : WhhF;
  const u16* xpp = xp + ((size_t)dir * B_ + b) * T_ * 400;
  const float* h0p = h0 + ((size_t)(2 * layer + dir) * B_ + b) * H_;
  const float* c0p = c0 + ((size_t)(2 * layer + dir) * B_ + b) * H_;
  __shared__ __align__(16) float hsh[104];
  __shared__ __align__(16) float gsh[400];
  __shared__ __align__(8)  float2 woddT[50 * 200];   // 80,000 B: [kpair][rowIdx]
  bool act = (tid < 200);
  // odd rows -> LDS (column-major by row index; one-time, coalesced)
  for (int i = tid; i < 10000; i += 256) {
    int row = i / 50, jp = i - 50 * row;   // row 0..199 -> W row 2row+1
    const float* p = Whh + (size_t)(2 * row + 1) * H_ + 2 * jp;
    woddT[jp * 200 + row] = make_float2(p[0], p[1]);
  }
  // even rows -> registers
  float4 w0[25];
  if (act) {
    const float4* p0 = (const float4*)(Whh + (size_t)(2 * tid) * H_);
    #pragma unroll
    for (int j = 0; j < 25; ++j) w0[j] = p0[j];
    #pragma unroll
    for (int j = 0; j < 25; ++j) PIN4(w0[j]);
  }
  if (tid < H_) hsh[tid] = h0p[tid];
  if (tid >= H_ && tid < 104) hsh[tid] = 0.f;
  float c = (tid < H_) ? c0p[tid] : 0.f;
  int sl = seqlen ? seqlen[b] : T_;
  __syncthreads();
  int tstep = dir ? -1 : 1;
  int t0 = dir ? (T_ - 1) : 0;
  ushort2 xc = make_ushort2(0, 0), xn = make_ushort2(0, 0);
  if (act) {
    xc = *(const ushort2*)(xpp + (size_t)t0 * 400 + 2 * tid);
    xn = *(const ushort2*)(xpp + (size_t)(t0 + tstep) * 400 + 2 * tid);
  }
  for (int tt = 0; tt < T_; ++tt) {
    int t = t0 + tstep * tt;
    ushort2 xn2 = make_ushort2(0, 0);
    if (act && tt + 2 < T_)
      xn2 = *(const ushort2*)(xpp + (size_t)(t + 2 * tstep) * 400 + 2 * tid);
    if (act) {
      float a0 = b2f(xc.x), a1 = b2f(xc.y);
      #pragma unroll
      for (int j = 0; j < 25; ++j) {
        float4 hv = *(const float4*)&hsh[4 * j];        // uniform -> broadcast
        float2 wv0 = woddT[(2 * j) * 200 + tid];        // conflict-free b64
        float2 wv1 = woddT[(2 * j + 1) * 200 + tid];
        a0 = fmaf(w0[j].x, hv.x, a0); a1 = fmaf(wv0.x, hv.x, a1);
        a0 = fmaf(w0[j].y, hv.y, a0); a1 = fmaf(wv0.y, hv.y, a1);
        a0 = fmaf(w0[j].z, hv.z, a0); a1 = fmaf(wv1.x, hv.z, a1);
        a0 = fmaf(w0[j].w, hv.w, a0); a1 = fmaf(wv1.y, hv.w, a1);
      }
      *(float2*)&gsh[2 * tid] = make_float2(a0, a1);
    }
    __syncthreads();
    if (tid < H_) {
      float gi = gsh[tid], gf = gsh[H_ + tid], gg = gsh[2 * H_ + tid], go = gsh[3 * H_ + tid];
      float si = 1.f / (1.f + __expf(-gi));
      float sf = 1.f / (1.f + __expf(-gf));
      float so = 1.f / (1.f + __expf(-go));
      float tg = 1.f - 2.f / (1.f + __expf(2.f * gg));
      c = fmaf(sf, c, si * tg);
      float tc = 1.f - 2.f / (1.f + __expf(2.f * c));
      float h = so * tc;
      hsh[tid] = h;
      outbuf[((size_t)b * T_ + t) * 200 + dir * H_ + tid] = (t < sl) ? (u16)f2b(h) : (u16)0;
    }
    __syncthreads();
    xc = xn; xn = xn2;
  }
}

// ---------------- CRF alpha (wg<B) + beta (wg>=B), one wave per batch -------
__global__ __launch_bounds__(64) void crf_k(
    const float* __restrict__ f, const float* __restrict__ g,
    float* __restrict__ alpha, float* __restrict__ beta)
{
  int wg = blockIdx.x;
  int lane = threadIdx.x;
  float gv[20], gn1[20], gn2[20], sv[20];
  #pragma unroll
  for (int q = 0; q < 20; ++q) { gv[q] = 0.f; gn1[q] = 0.f; gn2[q] = 0.f; }
  if (wg < B_) {
    int b = wg;
    const float* fp = f + (size_t)b * T_ * C_;
    const float* gp = g + (size_t)b * T_ * C_ * C_;
    float* ap = alpha + (size_t)b * T_ * C_;
    float a = 0.f;
    if (lane < C_) { a = fp[lane]; ap[lane] = a; }
    if (lane < C_) {
      #pragma unroll
      for (int q = 0; q < 20; ++q) gv[q] = gp[(size_t)1 * 400 + q * 20 + lane];
      #pragma unroll
      for (int q = 0; q < 20; ++q) gn1[q] = gp[(size_t)2 * 400 + q * 20 + lane];
    }
    for (int t = 1; t < T_; ++t) {
      if (t + 2 < T_ && lane < C_) {
        #pragma unroll
        for (int q = 0; q < 20; ++q) gn2[q] = gp[(size_t)(t + 2) * 400 + q * 20 + lane];
      }
      float ft = (lane < C_) ? fp[t * C_ + lane] : 0.f;
      float m = -3.0e38f;
      #pragma unroll
      for (int q = 0; q < 20; ++q) {
        float s = __shfl(a, q) + gv[q];
        sv[q] = s; m = fmaxf(m, s);
      }
      float sum = 0.f;
      #pragma unroll
      for (int q = 0; q < 20; ++q) sum += __expf(sv[q] - m);
      a = ft + m + __logf(sum);
      if (lane < C_) ap[(size_t)t * C_ + lane] = a;
      #pragma unroll
      for (int q = 0; q < 20; ++q) { gv[q] = gn1[q]; gn1[q] = gn2[q]; }
    }
  } else {
    int b = wg - B_;
    const float* fp = f + (size_t)b * T_ * C_;
    const float* gp = g + (size_t)b * T_ * C_ * C_;
    float* bp = beta + (size_t)b * T_ * C_;
    float bv = 0.f;
    if (lane < C_) bp[(size_t)(T_ - 1) * C_ + lane] = 0.f;
    if (lane < C_) {
      #pragma unroll
      for (int q = 0; q < 20; ++q) gv[q] = gp[(size_t)(T_ - 1) * 400 + lane * 20 + q];
      #pragma unroll
      for (int q = 0; q < 20; ++q) gn1[q] = gp[(size_t)(T_ - 2) * 400 + lane * 20 + q];
    }
    for (int t = T_ - 2; t >= 0; --t) {
      if (t >= 2 && lane < C_) {
        #pragma unroll
        for (int q = 0; q < 20; ++q) gn2[q] = gp[(size_t)(t - 1) * 400 + lane * 20 + q];
      }
      float w = ((lane < C_) ? fp[(t + 1) * C_ + lane] : 0.f) + bv;
      float m = -3.0e38f;
      #pragma unroll
      for (int q = 0; q < 20; ++q) {
        float s = gv[q] + __shfl(w, q);
        sv[q] = s; m = fmaxf(m, s);
      }
      float sum = 0.f;
      #pragma unroll
      for (int q = 0; q < 20; ++q) sum += __expf(sv[q] - m);
      bv = m + __logf(sum);
      if (lane < C_) bp[(size_t)t * C_ + lane] = bv;
      #pragma unroll
      for (int q = 0; q < 20; ++q) { gv[q] = gn1[q]; gn1[q] = gn2[q]; }
    }
  }
}

// ---------------- logZ per batch ----------------
__global__ void logz_k(const float* __restrict__ alpha, float* __restrict__ lz) {
  int b = blockIdx.x; int lane = threadIdx.x;
  float a = (lane < C_) ? alpha[((size_t)b * T_ + (T_ - 1)) * C_ + lane] : -3.0e38f;
  float m = a;
  #pragma unroll
  for (int o = 32; o > 0; o >>= 1) m = fmaxf(m, __shfl_xor(m, o));
  float e = (lane < C_) ? __expf(a - m) : 0.f;
  #pragma unroll
  for (int o = 32; o > 0; o >>= 1) e += __shfl_xor(e, o);
  if (lane == 0) lz[b] = m + __logf(e);
}

// ---------------- marginals = exp(alpha+beta-logZ) ----------------
__global__ void marg_k(const float* __restrict__ alpha, const float* __restrict__ beta,
                       const float* __restrict__ lz, float* __restrict__ out0) {
  size_t idx = (size_t)blockIdx.x * 256 + threadIdx.x;
  int b = (int)(idx / (T_ * C_));
  out0[idx] = __expf(alpha[idx] + beta[idx] - lz[b]);
}

extern "C" void kernel_launch(void* const* d_in, const int* in_sizes, int n_in,
                              void* d_out, int out_size, void* d_ws, size_t ws_size,
                              hipStream_t stream) {
  const int*   tok   = (const int*)d_in[0];
  const int*   seq   = (const int*)d_in[1];
  const float* emb   = (const float*)d_in[2];
  const float* Wih0  = (const float*)d_in[3];
  const float* Whh0  = (const float*)d_in[4];
  const float* bih0  = (const float*)d_in[5];
  const float* bhh0  = (const float*)d_in[6];
  const float* Wih0r = (const float*)d_in[7];
  const float* Whh0r = (const float*)d_in[8];
  const float* bih0r = (const float*)d_in[9];
  const float* bhh0r = (const float*)d_in[10];
  const float* Wih1  = (const float*)d_in[11];
  const float* Whh1  = (const float*)d_in[12];
  const float* bih1  = (const float*)d_in[13];
  const float* bhh1  = (const float*)d_in[14];
  const float* Wih1r = (const float*)d_in[15];
  const float* Whh1r = (const float*)d_in[16];
  const float* bih1r = (const float*)d_in[17];
  const float* bhh1r = (const float*)d_in[18];
  const float* fW    = (const float*)d_in[19];
  const float* fb    = (const float*)d_in[20];
  const float* gW    = (const float*)d_in[21];
  const float* gb    = (const float*)d_in[22];
  const float* h0    = (const float*)d_in[23];
  const float* c0    = (const float*)d_in[24];

  float* ws = (float*)d_ws;
  float* x0  = ws;                          // 4,194,304 floats
  u16*   xp  = (u16*)(ws + 4194304);        // 104,857,600 bf16
  u16*   x1  = (u16*)(ws + 109051904);      // 26,214,400 bf16
  float* lz  = ws + 135266304;              // 128 floats

  float* out   = (float*)d_out;
  float* f_out = out + 2621440;
  float* g_out = out + 5242880;
  float* a_out = out + 57671680;
  float* b_out = out + 60293120;

  embed_k<<<16384, 256, 0, stream>>>(tok, emb, x0);

  dim3 g400(2048, 7), g20(2048, 1);
  // layer 0 input projections (K=32): fp32 A -> bf16 xp
  gemm_mfma_t<0,1><<<g400, 256, 0, stream>>>(x0, Wih0,  bih0,  bhh0,  xp,                    32, 400, 400);
  gemm_mfma_t<0,1><<<g400, 256, 0, stream>>>(x0, Wih0r, bih0r, bhh0r, xp + (size_t)52428800, 32, 400, 400);
  lstm_scan<<<256, 256, 0, stream>>>(xp, Whh0, Whh0r, h0, c0, nullptr, x1, 0);
  // layer 1 input projections (K=200): bf16 A -> bf16 xp
  gemm_mfma_t<1,1><<<g400, 256, 0, stream>>>(x1, Wih1,  bih1,  bhh1,  xp,                    200, 400, 400);
  gemm_mfma_t<1,1><<<g400, 256, 0, stream>>>(x1, Wih1r, bih1r, bhh1r, xp + (size_t)52428800, 200, 400, 400);
  lstm_scan<<<256, 256, 0, stream>>>(xp, Whh1, Whh1r, h0, c0, seq, x1, 1);
  // emissions + transitions: bf16 A -> fp32 outputs
  gemm_mfma_t<1,0><<<g20,  256, 0, stream>>>(x1, fW, fb, nullptr, f_out, 200, 20,  20);
  gemm_mfma_t<1,0><<<g400, 256, 0, stream>>>(x1, gW, gb, nullptr, g_out, 200, 400, 400);
  // CRF forward/backward
  crf_k<<<256, 64, 0, stream>>>(f_out, g_out, a_out, b_out);
  logz_k<<<128, 64, 0, stream>>>(a_out, lz);
  marg_k<<<10240, 256, 0, stream>>>(a_out, b_out, lz, out);
}

// Round 14
// 3041.624 us; speedup vs baseline: 1.5102x; 1.5102x over previous
//
#include <hip/hip_runtime.h>
#include <hip/hip_bf16.h>

#define B_ 128
#define T_ 1024
#define E_ 32
#define H_ 100
#define C_ 20
#define M_ (B_*T_)   // 131072

typedef __attribute__((ext_vector_type(8))) short bf16x8v;
typedef __attribute__((ext_vector_type(4))) float f32x4v;
typedef __attribute__((ext_vector_type(2))) _Float16 h2v;
typedef unsigned short u16;
typedef unsigned int u32;

static __device__ __forceinline__ short f2b(float x) {
  union { __hip_bfloat16 b; short s; } u;
  u.b = __float2bfloat16(x);
  return u.s;
}
static __device__ __forceinline__ float b2f(u16 x) {
  return __uint_as_float(((u32)x) << 16);
}

#if __has_builtin(__builtin_amdgcn_fdot2)
#define FDOT2(w, p, c) __builtin_amdgcn_fdot2((w), (p), (c), false)
#else
static __device__ __forceinline__ float FDOT2(h2v w, h2v p, float c) {
  return fmaf((float)w[1], (float)p[1], fmaf((float)w[0], (float)p[0], c));
}
#endif

// ---------------- embedding lookup ----------------
__global__ void embed_k(const int* __restrict__ tok, const float* __restrict__ emb,
                        float* __restrict__ x0) {
  int idx = blockIdx.x * 256 + threadIdx.x;   // over M_*E_ = 4194304
  int bt = idx >> 5;
  int e  = idx & 31;
  x0[idx] = emb[tok[bt] * E_ + e];
}

// ---------------- bf16 MFMA GEMM: C[M,N] = A[M,K] @ W[N,K]^T + b1 + b2 ------
template<int ABF, int OBF>
__global__ __launch_bounds__(256) void gemm_mfma_t(
    const void* __restrict__ Av, const float* __restrict__ W,
    const float* __restrict__ b1, const float* __restrict__ b2,
    void* __restrict__ Cv, int K, int N, int ldc)
{
  __shared__ short as[64 * 40];   // [row][k] pad 40
  __shared__ short ws[64 * 40];   // [col][k]
  const float* Af = (const float*)Av;
  const u16*   Ab = (const u16*)Av;
  float* Cf = (float*)Cv;
  u16*   Cb = (u16*)Cv;
  int tid = threadIdx.x, lane = tid & 63, w = tid >> 6;
  int lr = lane & 15, lq = lane >> 4;
  size_t m0 = (size_t)blockIdx.x * 64;
  int n0 = blockIdx.y * 64;
  int srow = tid >> 2;            // staging row 0..63
  int sk = (tid & 3) * 8;         // staging k offset 0,8,16,24
  bool wok = (n0 + srow) < N;
  const float* Wp = wok ? (W + (size_t)(n0 + srow) * K + sk) : W;
  size_t arow = (m0 + srow) * (size_t)K;
  f32x4v acc[4];
  #pragma unroll
  for (int r = 0; r < 4; ++r) acc[r] = (f32x4v){0.f, 0.f, 0.f, 0.f};
  int ksteps = (K + 31) / 32;
  for (int ks = 0; ks < ksteps; ++ks) {
    int kk = ks * 32;
    bf16x8v av, wv;
    if (kk + sk + 7 < K) {
      if (ABF) {
        av = *(const bf16x8v*)(Ab + arow + kk + sk);
      } else {
        float4 a0 = *(const float4*)(Af + arow + kk + sk);
        float4 a1 = *(const float4*)(Af + arow + kk + sk + 4);
        av[0]=f2b(a0.x); av[1]=f2b(a0.y); av[2]=f2b(a0.z); av[3]=f2b(a0.w);
        av[4]=f2b(a1.x); av[5]=f2b(a1.y); av[6]=f2b(a1.z); av[7]=f2b(a1.w);
      }
      if (wok) {
        float4 w0 = *(const float4*)(Wp + kk);
        float4 w1 = *(const float4*)(Wp + kk + 4);
        wv[0]=f2b(w0.x); wv[1]=f2b(w0.y); wv[2]=f2b(w0.z); wv[3]=f2b(w0.w);
        wv[4]=f2b(w1.x); wv[5]=f2b(w1.y); wv[6]=f2b(w1.z); wv[7]=f2b(w1.w);
      } else {
        #pragma unroll
        for (int j = 0; j < 8; ++j) wv[j] = 0;
      }
    } else {
      #pragma unroll
      for (int j = 0; j < 8; ++j) {
        int k = kk + sk + j;
        av[j] = (k < K) ? (ABF ? (short)Ab[arow + k] : f2b(Af[arow + k])) : (short)0;
        wv[j] = (wok && k < K) ? f2b(W[(size_t)(n0 + srow) * K + k]) : (short)0;
      }
    }
    *(bf16x8v*)&as[srow * 40 + sk] = av;
    *(bf16x8v*)&ws[srow * 40 + sk] = wv;
    __syncthreads();
    bf16x8v bf = *(const bf16x8v*)&ws[(16 * w + lr) * 40 + 8 * lq];
    #pragma unroll
    for (int r = 0; r < 4; ++r) {
      bf16x8v af = *(const bf16x8v*)&as[(16 * r + lr) * 40 + 8 * lq];
      acc[r] = __builtin_amdgcn_mfma_f32_16x16x32_bf16(af, bf, acc[r], 0, 0, 0);
    }
    __syncthreads();
  }
  int col = n0 + 16 * w + lr;
  if (col < N) {
    float bv = (b1 ? b1[col] : 0.f) + (b2 ? b2[col] : 0.f);
    #pragma unroll
    for (int r = 0; r < 4; ++r)
      #pragma unroll
      for (int rg = 0; rg < 4; ++rg) {
        size_t off = (m0 + 16 * r + 4 * lq + rg) * (size_t)ldc + col;
        float v = acc[r][rg] + bv;
        if (OBF) Cb[off] = (u16)f2b(v); else Cf[off] = v;
      }
  }
}

// ---------------- LSTM scan, f16-packed register weights + v_dot2 ----------
// r13 post-mortem: the 100-VGPR pinned array DID stay resident (alloc 140,
// first no-spill in 13 rounds) but 50 per-lane ds_read_b64/step on 1 wave/SIMD
// cost ~4000cy/step. Fix: put BOTH rows in registers by halving their size --
// f16-packed half2 (52+52 u32 = 104 VGPR, demand ~135 <= proven 140 grant) and
// consume via v_dot2_f32_f16 (2 MAC/instr, fp32 accumulate): 104 dot2 + 13
// UNIFORM b128 broadcasts (r8: broadcast is cheap) per step, ~0 LDS conflicts.
// f16 (10-bit mantissa) is more accurate than the bf16 paths already passing.
__global__ __launch_bounds__(256, 1) void lstm_scan(
    const u16* __restrict__ xp,
    const float* __restrict__ WhhF, const float* __restrict__ WhhR,
    const float* __restrict__ h0, const float* __restrict__ c0, // [4][B][H]
    const int* __restrict__ seqlen,   // null => no mask
    u16* __restrict__ outbuf,         // [B][T][200] bf16, dir*100 offset
    int layer)
{
  int wg = blockIdx.x; int dir = wg & 1; int b = wg >> 1;
  int tid = threadIdx.x;
  const float* Whh = dir ? WhhR : WhhF;
  const u16* xpp = xp + ((size_t)dir * B_ + b) * T_ * 400;
  const float* h0p = h0 + ((size_t)(2 * layer + dir) * B_ + b) * H_;
  const float* c0p = c0 + ((size_t)(2 * layer + dir) * B_ + b) * H_;
  __shared__ __align__(16) float gsh[400];
  __shared__ __align__(16) _Float16 hph[112];   // h as f16; [100..111] = 0
  bool act = (tid < 200);
  // pack rows 2tid, 2tid+1 into half2 registers (one-time)
  u32 w0p[52], w1p[52];
  if (act) {
    const float* r0 = Whh + (size_t)(2 * tid) * H_;
    const float* r1 = Whh + (size_t)(2 * tid + 1) * H_;
    #pragma unroll
    for (int j = 0; j < 52; ++j) {
      float a0 = (j < 50) ? r0[2 * j] : 0.f;
      float a1 = (j < 50) ? r0[2 * j + 1] : 0.f;
      float c0v = (j < 50) ? r1[2 * j] : 0.f;
      float c1v = (j < 50) ? r1[2 * j + 1] : 0.f;
      w0p[j] = __builtin_bit_cast(u32, (h2v){(_Float16)a0, (_Float16)a1});
      w1p[j] = __builtin_bit_cast(u32, (h2v){(_Float16)c0v, (_Float16)c1v});
    }
    #pragma unroll
    for (int j = 0; j < 52; ++j)
      asm volatile("" : "+v"(w0p[j]), "+v"(w1p[j]));
  }
  if (tid < 112) hph[tid] = (_Float16)((tid < H_) ? h0p[tid] : 0.f);
  float c = (tid < H_) ? c0p[tid] : 0.f;
  int sl = seqlen ? seqlen[b] : T_;
  __syncthreads();
  int tstep = dir ? -1 : 1;
  int t0 = dir ? (T_ - 1) : 0;
  ushort2 xc = make_ushort2(0, 0), xn = make_ushort2(0, 0);
  if (act) {
    xc = *(const ushort2*)(xpp + (size_t)t0 * 400 + 2 * tid);
    xn = *(const ushort2*)(xpp + (size_t)(t0 + tstep) * 400 + 2 * tid);
  }
  for (int tt = 0; tt < T_; ++tt) {
    int t = t0 + tstep * tt;
    ushort2 xn2 = make_ushort2(0, 0);
    if (act && tt + 2 < T_)
      xn2 = *(const ushort2*)(xpp + (size_t)(t + 2 * tstep) * 400 + 2 * tid);
    if (act) {
      float a0 = b2f(xc.x), a1 = b2f(xc.y);
      #pragma unroll
      for (int q = 0; q < 13; ++q) {
        f32x4v hp = ((const f32x4v*)hph)[q];   // uniform addr -> broadcast
        #pragma unroll
        for (int i = 0; i < 4; ++i) {
          h2v p = __builtin_bit_cast(h2v, hp[i]);
          a0 = FDOT2(__builtin_bit_cast(h2v, w0p[4 * q + i]), p, a0);
          a1 = FDOT2(__builtin_bit_cast(h2v, w1p[4 * q + i]), p, a1);
        }
      }
      *(float2*)&gsh[2 * tid] = make_float2(a0, a1);
    }
    __syncthreads();
    if (tid < H_) {
      float gi = gsh[tid], gf = gsh[H_ + tid], gg = gsh[2 * H_ + tid], go = gsh[3 * H_ + tid];
      float si = 1.f / (1.f + __expf(-gi));
      float sf = 1.f / (1.f + __expf(-gf));
      float so = 1.f / (1.f + __expf(-go));
      float tg = 1.f - 2.f / (1.f + __expf(2.f * gg));
      c = fmaf(sf, c, si * tg);
      float tc = 1.f - 2.f / (1.f + __expf(2.f * c));
      float h = so * tc;
      hph[tid] = (_Float16)h;
      outbuf[((size_t)b * T_ + t) * 200 + dir * H_ + tid] = (t < sl) ? (u16)f2b(h) : (u16)0;
    }
    __syncthreads();
    xc = xn; xn = xn2;
  }
}

// ---------------- CRF alpha (wg<B) + beta (wg>=B), one wave per batch -------
__global__ __launch_bounds__(64) void crf_k(
    const float* __restrict__ f, const float* __restrict__ g,
    float* __restrict__ alpha, float* __restrict__ beta)
{
  int wg = blockIdx.x;
  int lane = threadIdx.x;
  float gv[20], gn1[20], gn2[20], sv[20];
  #pragma unroll
  for (int q = 0; q < 20; ++q) { gv[q] = 0.f; gn1[q] = 0.f; gn2[q] = 0.f; }
  if (wg < B_) {
    int b = wg;
    const float* fp = f + (size_t)b * T_ * C_;
    const float* gp = g + (size_t)b * T_ * C_ * C_;
    float* ap = alpha + (size_t)b * T_ * C_;
    float a = 0.f;
    if (lane < C_) { a = fp[lane]; ap[lane] = a; }
    if (lane < C_) {
      #pragma unroll
      for (int q = 0; q < 20; ++q) gv[q] = gp[(size_t)1 * 400 + q * 20 + lane];
      #pragma unroll
      for (int q = 0; q < 20; ++q) gn1[q] = gp[(size_t)2 * 400 + q * 20 + lane];
    }
    for (int t = 1; t < T_; ++t) {
      if (t + 2 < T_ && lane < C_) {
        #pragma unroll
        for (int q = 0; q < 20; ++q) gn2[q] = gp[(size_t)(t + 2) * 400 + q * 20 + lane];
      }
      float ft = (lane < C_) ? fp[t * C_ + lane] : 0.f;
      float m = -3.0e38f;
      #pragma unroll
      for (int q = 0; q < 20; ++q) {
        float s = __shfl(a, q) + gv[q];
        sv[q] = s; m = fmaxf(m, s);
      }
      float sum = 0.f;
      #pragma unroll
      for (int q = 0; q < 20; ++q) sum += __expf(sv[q] - m);
      a = ft + m + __logf(sum);
      if (lane < C_) ap[(size_t)t * C_ + lane] = a;
      #pragma unroll
      for (int q = 0; q < 20; ++q) { gv[q] = gn1[q]; gn1[q] = gn2[q]; }
    }
  } else {
    int b = wg - B_;
    const float* fp = f + (size_t)b * T_ * C_;
    const float* gp = g + (size_t)b * T_ * C_ * C_;
    float* bp = beta + (size_t)b * T_ * C_;
    float bv = 0.f;
    if (lane < C_) bp[(size_t)(T_ - 1) * C_ + lane] = 0.f;
    if (lane < C_) {
      #pragma unroll
      for (int q = 0; q < 20; ++q) gv[q] = gp[(size_t)(T_ - 1) * 400 + lane * 20 + q];
      #pragma unroll
      for (int q = 0; q < 20; ++q) gn1[q] = gp[(size_t)(T_ - 2) * 400 + lane * 20 + q];
    }
    for (int t = T_ - 2; t >= 0; --t) {
      if (t >= 2 && lane < C_) {
        #pragma unroll
        for (int q = 0; q < 20; ++q) gn2[q] = gp[(size_t)(t - 1) * 400 + lane * 20 + q];
      }
      float w = ((lane < C_) ? fp[(t + 1) * C_ + lane] : 0.f) + bv;
      float m = -3.0e38f;
      #pragma unroll
      for (int q = 0; q < 20; ++q) {
        float s = gv[q] + __shfl(w, q);
        sv[q] = s; m = fmaxf(m, s);
      }
      float sum = 0.f;
      #pragma unroll
      for (int q = 0; q < 20; ++q) sum += __expf(sv[q] - m);
      bv = m + __logf(sum);
      if (lane < C_) bp[(size_t)t * C_ + lane] = bv;
      #pragma unroll
      for (int q = 0; q < 20; ++q) { gv[q] = gn1[q]; gn1[q] = gn2[q]; }
    }
  }
}

// ---------------- logZ per batch ----------------
__global__ void logz_k(const float* __restrict__ alpha, float* __restrict__ lz) {
  int b = blockIdx.x; int lane = threadIdx.x;
  float a = (lane < C_) ? alpha[((size_t)b * T_ + (T_ - 1)) * C_ + lane] : -3.0e38f;
  float m = a;
  #pragma unroll
  for (int o = 32; o > 0; o >>= 1) m = fmaxf(m, __shfl_xor(m, o));
  float e = (lane < C_) ? __expf(a - m) : 0.f;
  #pragma unroll
  for (int o = 32; o > 0; o >>= 1) e += __shfl_xor(e, o);
  if (lane == 0) lz[b] = m + __logf(e);
}

// ---------------- marginals = exp(alpha+beta-logZ) ----------------
__global__ void marg_k(const float* __restrict__ alpha, const float* __restrict__ beta,
                       const float* __restrict__ lz, float* __restrict__ out0) {
  size_t idx = (size_t)blockIdx.x * 256 + threadIdx.x;
  int b = (int)(idx / (T_ * C_));
  out0[idx] = __expf(alpha[idx] + beta[idx] - lz[b]);
}

extern "C" void kernel_launch(void* const* d_in, const int* in_sizes, int n_in,
                              void* d_out, int out_size, void* d_ws, size_t ws_size,
                              hipStream_t stream) {
  const int*   tok   = (const int*)d_in[0];
  const int*   seq   = (const int*)d_in[1];
  const float* emb   = (const float*)d_in[2];
  const float* Wih0  = (const float*)d_in[3];
  const float* Whh0  = (const float*)d_in[4];
  const float* bih0  = (const float*)d_in[5];
  const float* bhh0  = (const float*)d_in[6];
  const float* Wih0r = (const float*)d_in[7];
  const float* Whh0r = (const float*)d_in[8];
  const float* bih0r = (const float*)d_in[9];
  const float* bhh0r = (const float*)d_in[10];
  const float* Wih1  = (const float*)d_in[11];
  const float* Whh1  = (const float*)d_in[12];
  const float* bih1  = (const float*)d_in[13];
  const float* bhh1  = (const float*)d_in[14];
  const float* Wih1r = (const float*)d_in[15];
  const float* Whh1r = (const float*)d_in[16];
  const float* bih1r = (const float*)d_in[17];
  const float* bhh1r = (const float*)d_in[18];
  const float* fW    = (const float*)d_in[19];
  const float* fb    = (const float*)d_in[20];
  const float* gW    = (const float*)d_in[21];
  const float* gb    = (const float*)d_in[22];
  const float* h0    = (const float*)d_in[23];
  const float* c0    = (const float*)d_in[24];

  float* ws = (float*)d_ws;
  float* x0  = ws;                          // 4,194,304 floats
  u16*   xp  = (u16*)(ws + 4194304);        // 104,857,600 bf16
  u16*   x1  = (u16*)(ws + 109051904);      // 26,214,400 bf16
  float* lz  = ws + 135266304;              // 128 floats

  float* out   = (float*)d_out;
  float* f_out = out + 2621440;
  float* g_out = out + 5242880;
  float* a_out = out + 57671680;
  float* b_out = out + 60293120;

  embed_k<<<16384, 256, 0, stream>>>(tok, emb, x0);

  dim3 g400(2048, 7), g20(2048, 1);
  // layer 0 input projections (K=32): fp32 A -> bf16 xp
  gemm_mfma_t<0,1><<<g400, 256, 0, stream>>>(x0, Wih0,  bih0,  bhh0,  xp,                    32, 400, 400);
  gemm_mfma_t<0,1><<<g400, 256, 0, stream>>>(x0, Wih0r, bih0r, bhh0r, xp + (size_t)52428800, 32, 400, 400);
  lstm_scan<<<256, 256, 0, stream>>>(xp, Whh0, Whh0r, h0, c0, nullptr, x1, 0);
  // layer 1 input projections (K=200): bf16 A -> bf16 xp
  gemm_mfma_t<1,1><<<g400, 256, 0, stream>>>(x1, Wih1,  bih1,  bhh1,  xp,                    200, 400, 400);
  gemm_mfma_t<1,1><<<g400, 256, 0, stream>>>(x1, Wih1r, bih1r, bhh1r, xp + (size_t)52428800, 200, 400, 400);
  lstm_scan<<<256, 256, 0, stream>>>(xp, Whh1, Whh1r, h0, c0, seq, x1, 1);
  // emissions + transitions: bf16 A -> fp32 outputs
  gemm_mfma_t<1,0><<<g20,  256, 0, stream>>>(x1, fW, fb, nullptr, f_out, 200, 20,  20);
  gemm_mfma_t<1,0><<<g400, 256, 0, stream>>>(x1, gW, gb, nullptr, g_out, 200, 400, 400);
  // CRF forward/backward
  crf_k<<<256, 64, 0, stream>>>(f_out, g_out, a_out, b_out);
  logz_k<<<128, 64, 0, stream>>>(a_out, lz);
  marg_k<<<10240, 256, 0, stream>>>(a_out, b_out, lz, out);
}

// Round 15
// 2738.801 us; speedup vs baseline: 1.6772x; 1.1106x over previous
//
#include <hip/hip_runtime.h>
#include <hip/hip_bf16.h>

#define B_ 128
#define T_ 1024
#define E_ 32
#define H_ 100
#define C_ 20
#define M_ (B_*T_)   // 131072

typedef __attribute__((ext_vector_type(8))) short bf16x8v;
typedef __attribute__((ext_vector_type(4))) float f32x4v;
typedef __attribute__((ext_vector_type(2))) _Float16 h2v;
typedef unsigned short u16;
typedef unsigned int u32;

static __device__ __forceinline__ short f2b(float x) {
  union { __hip_bfloat16 b; short s; } u;
  u.b = __float2bfloat16(x);
  return u.s;
}
static __device__ __forceinline__ float b2f(u16 x) {
  return __uint_as_float(((u32)x) << 16);
}

#if __has_builtin(__builtin_amdgcn_fdot2)
#define FDOT2(w, p, c) __builtin_amdgcn_fdot2((w), (p), (c), false)
#else
static __device__ __forceinline__ float FDOT2(h2v w, h2v p, float c) {
  return fmaf((float)w[1], (float)p[1], fmaf((float)w[0], (float)p[0], c));
}
#endif

// ---------------- embedding lookup ----------------
__global__ void embed_k(const int* __restrict__ tok, const float* __restrict__ emb,
                        float* __restrict__ x0) {
  int idx = blockIdx.x * 256 + threadIdx.x;   // over M_*E_ = 4194304
  int bt = idx >> 5;
  int e  = idx & 31;
  x0[idx] = emb[tok[bt] * E_ + e];
}

// ---------------- bf16 MFMA GEMM: C[M,N] = A[M,K] @ W[N,K]^T + b1 + b2 ------
template<int ABF, int OBF>
__global__ __launch_bounds__(256) void gemm_mfma_t(
    const void* __restrict__ Av, const float* __restrict__ W,
    const float* __restrict__ b1, const float* __restrict__ b2,
    void* __restrict__ Cv, int K, int N, int ldc)
{
  __shared__ short as[64 * 40];   // [row][k] pad 40
  __shared__ short ws[64 * 40];   // [col][k]
  const float* Af = (const float*)Av;
  const u16*   Ab = (const u16*)Av;
  float* Cf = (float*)Cv;
  u16*   Cb = (u16*)Cv;
  int tid = threadIdx.x, lane = tid & 63, w = tid >> 6;
  int lr = lane & 15, lq = lane >> 4;
  size_t m0 = (size_t)blockIdx.x * 64;
  int n0 = blockIdx.y * 64;
  int srow = tid >> 2;            // staging row 0..63
  int sk = (tid & 3) * 8;         // staging k offset 0,8,16,24
  bool wok = (n0 + srow) < N;
  const float* Wp = wok ? (W + (size_t)(n0 + srow) * K + sk) : W;
  size_t arow = (m0 + srow) * (size_t)K;
  f32x4v acc[4];
  #pragma unroll
  for (int r = 0; r < 4; ++r) acc[r] = (f32x4v){0.f, 0.f, 0.f, 0.f};
  int ksteps = (K + 31) / 32;
  for (int ks = 0; ks < ksteps; ++ks) {
    int kk = ks * 32;
    bf16x8v av, wv;
    if (kk + sk + 7 < K) {
      if (ABF) {
        av = *(const bf16x8v*)(Ab + arow + kk + sk);
      } else {
        float4 a0 = *(const float4*)(Af + arow + kk + sk);
        float4 a1 = *(const float4*)(Af + arow + kk + sk + 4);
        av[0]=f2b(a0.x); av[1]=f2b(a0.y); av[2]=f2b(a0.z); av[3]=f2b(a0.w);
        av[4]=f2b(a1.x); av[5]=f2b(a1.y); av[6]=f2b(a1.z); av[7]=f2b(a1.w);
      }
      if (wok) {
        float4 w0 = *(const float4*)(Wp + kk);
        float4 w1 = *(const float4*)(Wp + kk + 4);
        wv[0]=f2b(w0.x); wv[1]=f2b(w0.y); wv[2]=f2b(w0.z); wv[3]=f2b(w0.w);
        wv[4]=f2b(w1.x); wv[5]=f2b(w1.y); wv[6]=f2b(w1.z); wv[7]=f2b(w1.w);
      } else {
        #pragma unroll
        for (int j = 0; j < 8; ++j) wv[j] = 0;
      }
    } else {
      #pragma unroll
      for (int j = 0; j < 8; ++j) {
        int k = kk + sk + j;
        av[j] = (k < K) ? (ABF ? (short)Ab[arow + k] : f2b(Af[arow + k])) : (short)0;
        wv[j] = (wok && k < K) ? f2b(W[(size_t)(n0 + srow) * K + k]) : (short)0;
      }
    }
    *(bf16x8v*)&as[srow * 40 + sk] = av;
    *(bf16x8v*)&ws[srow * 40 + sk] = wv;
    __syncthreads();
    bf16x8v bf = *(const bf16x8v*)&ws[(16 * w + lr) * 40 + 8 * lq];
    #pragma unroll
    for (int r = 0; r < 4; ++r) {
      bf16x8v af = *(const bf16x8v*)&as[(16 * r + lr) * 40 + 8 * lq];
      acc[r] = __builtin_amdgcn_mfma_f32_16x16x32_bf16(af, bf, acc[r], 0, 0, 0);
    }
    __syncthreads();
  }
  int col = n0 + 16 * w + lr;
  if (col < N) {
    float bv = (b1 ? b1[col] : 0.f) + (b2 ? b2[col] : 0.f);
    #pragma unroll
    for (int r = 0; r < 4; ++r)
      #pragma unroll
      for (int rg = 0; rg < 4; ++rg) {
        size_t off = (m0 + 16 * r + 4 * lq + rg) * (size_t)ldc + col;
        float v = acc[r][rg] + bv;
        if (OBF) Cb[off] = (u16)f2b(v); else Cf[off] = v;
      }
  }
}

// ---------------- LSTM scan, f16-packed register weights + v_dot2 ----------
// (r14 winner: first spill-free scan; keep unchanged)
__global__ __launch_bounds__(256, 1) void lstm_scan(
    const u16* __restrict__ xp,
    const float* __restrict__ WhhF, const float* __restrict__ WhhR,
    const float* __restrict__ h0, const float* __restrict__ c0, // [4][B][H]
    const int* __restrict__ seqlen,   // null => no mask
    u16* __restrict__ outbuf,         // [B][T][200] bf16, dir*100 offset
    int layer)
{
  int wg = blockIdx.x; int dir = wg & 1; int b = wg >> 1;
  int tid = threadIdx.x;
  const float* Whh = dir ? WhhR : WhhF;
  const u16* xpp = xp + ((size_t)dir * B_ + b) * T_ * 400;
  const float* h0p = h0 + ((size_t)(2 * layer + dir) * B_ + b) * H_;
  const float* c0p = c0 + ((size_t)(2 * layer + dir) * B_ + b) * H_;
  __shared__ __align__(16) float gsh[400];
  __shared__ __align__(16) _Float16 hph[112];   // h as f16; [100..111] = 0
  bool act = (tid < 200);
  u32 w0p[52], w1p[52];
  if (act) {
    const float* r0 = Whh + (size_t)(2 * tid) * H_;
    const float* r1 = Whh + (size_t)(2 * tid + 1) * H_;
    #pragma unroll
    for (int j = 0; j < 52; ++j) {
      float a0 = (j < 50) ? r0[2 * j] : 0.f;
      float a1 = (j < 50) ? r0[2 * j + 1] : 0.f;
      float c0v = (j < 50) ? r1[2 * j] : 0.f;
      float c1v = (j < 50) ? r1[2 * j + 1] : 0.f;
      w0p[j] = __builtin_bit_cast(u32, (h2v){(_Float16)a0, (_Float16)a1});
      w1p[j] = __builtin_bit_cast(u32, (h2v){(_Float16)c0v, (_Float16)c1v});
    }
    #pragma unroll
    for (int j = 0; j < 52; ++j)
      asm volatile("" : "+v"(w0p[j]), "+v"(w1p[j]));
  }
  if (tid < 112) hph[tid] = (_Float16)((tid < H_) ? h0p[tid] : 0.f);
  float c = (tid < H_) ? c0p[tid] : 0.f;
  int sl = seqlen ? seqlen[b] : T_;
  __syncthreads();
  int tstep = dir ? -1 : 1;
  int t0 = dir ? (T_ - 1) : 0;
  ushort2 xc = make_ushort2(0, 0), xn = make_ushort2(0, 0);
  if (act) {
    xc = *(const ushort2*)(xpp + (size_t)t0 * 400 + 2 * tid);
    xn = *(const ushort2*)(xpp + (size_t)(t0 + tstep) * 400 + 2 * tid);
  }
  for (int tt = 0; tt < T_; ++tt) {
    int t = t0 + tstep * tt;
    ushort2 xn2 = make_ushort2(0, 0);
    if (act && tt + 2 < T_)
      xn2 = *(const ushort2*)(xpp + (size_t)(t + 2 * tstep) * 400 + 2 * tid);
    if (act) {
      float a0 = b2f(xc.x), a1 = b2f(xc.y);
      #pragma unroll
      for (int q = 0; q < 13; ++q) {
        f32x4v hp = ((const f32x4v*)hph)[q];   // uniform addr -> broadcast
        #pragma unroll
        for (int i = 0; i < 4; ++i) {
          h2v p = __builtin_bit_cast(h2v, hp[i]);
          a0 = FDOT2(__builtin_bit_cast(h2v, w0p[4 * q + i]), p, a0);
          a1 = FDOT2(__builtin_bit_cast(h2v, w1p[4 * q + i]), p, a1);
        }
      }
      *(float2*)&gsh[2 * tid] = make_float2(a0, a1);
    }
    __syncthreads();
    if (tid < H_) {
      float gi = gsh[tid], gf = gsh[H_ + tid], gg = gsh[2 * H_ + tid], go = gsh[3 * H_ + tid];
      float si = 1.f / (1.f + __expf(-gi));
      float sf = 1.f / (1.f + __expf(-gf));
      float so = 1.f / (1.f + __expf(-go));
      float tg = 1.f - 2.f / (1.f + __expf(2.f * gg));
      c = fmaf(sf, c, si * tg);
      float tc = 1.f - 2.f / (1.f + __expf(2.f * c));
      float h = so * tc;
      hph[tid] = (_Float16)h;
      outbuf[((size_t)b * T_ + t) * 200 + dir * H_ + tid] = (t < sl) ? (u16)f2b(h) : (u16)0;
    }
    __syncthreads();
    xc = xn; xn = xn2;
  }
}

// ---------------- CRF with LDS ring staging ----------------
// r14 post-mortem: crf was the RA disease again -- demand ~100 (gv/gn1/gn2/sv
// register rings), alloc 60 -> scratch reloads in the serial chain, 2160cy/
// step, 922us. Fix: g rows staged in a 4-slot LDS ring (6.4KB): lanes 0..49
// load 8 floats (2x float4) one step before the ds_write_b128 (hides L2/L3
// latency), consumed 2 steps later. Running vector a / w=f+b lives in aw[20]
// LDS, read as 5 uniform b128 broadcasts (cheap). alpha reads column j
// (consecutive -> conflict-free); beta reads its row via 5 b128. max/sum via
// 4-wide trees. Register demand ~55 (s[20] + 16 staging) -> no spill.
// Single wave per block -> wave-synchronous, no barriers.
__global__ __launch_bounds__(64) void crf_k(
    const float* __restrict__ f, const float* __restrict__ g,
    float* __restrict__ alpha, float* __restrict__ beta)
{
  int wg = blockIdx.x;
  int lane = threadIdx.x;
  __shared__ __align__(16) float gl[4][400];   // ring: row r -> slot r&3
  __shared__ __align__(16) float aw[20];       // alpha: a[t-1]; beta: f[t+1]+b[t+1]
  bool stv = lane < 50;
  int p0 = 8 * lane;                           // this lane stages floats [p0,p0+8)
  float4 rA0, rA1, rB0, rB1;                   // in-flight staged row (reg ring)

  if (wg < B_) {
    // ---------------- alpha ----------------
    int b = wg;
    const float* fp = f + (size_t)b * T_ * C_;
    const float* gp = g + (size_t)b * T_ * C_ * C_;
    float* ap = alpha + (size_t)b * T_ * C_;
    if (lane < C_) {
      float a0 = fp[lane];
      ap[lane] = a0;
      aw[lane] = a0;
    }
    if (stv) {
      float4 v0 = *(const float4*)(gp + 400 + p0);
      float4 v1 = *(const float4*)(gp + 404 + p0);
      *(float4*)&gl[1 & 3][p0] = v0;  *(float4*)&gl[1 & 3][p0 + 4] = v1;
      v0 = *(const float4*)(gp + 800 + p0);
      v1 = *(const float4*)(gp + 804 + p0);
      *(float4*)&gl[2 & 3][p0] = v0;  *(float4*)&gl[2 & 3][p0 + 4] = v1;
      rA0 = *(const float4*)(gp + 1200 + p0);       // row 3 in flight
      rA1 = *(const float4*)(gp + 1204 + p0);
    }
    for (int t = 1; t < T_; ++t) {
      if (stv && (t + 3 < T_)) {                    // issue loads for row t+3
        rB0 = *(const float4*)(gp + (size_t)(t + 3) * 400 + p0);
        rB1 = *(const float4*)(gp + (size_t)(t + 3) * 400 + p0 + 4);
      }
      if (lane < C_) {
        const float* gr = &gl[t & 3][0];
        float ft = fp[(size_t)t * C_ + lane];       // issued early, used late
        float awv[20];
        #pragma unroll
        for (int q = 0; q < 5; ++q)
          *(f32x4v*)&awv[4 * q] = ((const f32x4v*)aw)[q];   // uniform b128
        float s[20];
        #pragma unroll
        for (int i = 0; i < 20; ++i)
          s[i] = awv[i] + gr[i * 20 + lane];        // consecutive -> no conflict
        float m4[5];
        #pragma unroll
        for (int q = 0; q < 5; ++q)
          m4[q] = fmaxf(fmaxf(s[4*q], s[4*q+1]), fmaxf(s[4*q+2], s[4*q+3]));
        float m = fmaxf(fmaxf(m4[0], m4[1]), fmaxf(fmaxf(m4[2], m4[3]), m4[4]));
        float e4[5];
        #pragma unroll
        for (int q = 0; q < 5; ++q) {
          float e0 = __expf(s[4*q] - m),   e1 = __expf(s[4*q+1] - m);
          float e2 = __expf(s[4*q+2] - m), e3 = __expf(s[4*q+3] - m);
          e4[q] = (e0 + e1) + (e2 + e3);
        }
        float sum = (e4[0] + e4[1]) + ((e4[2] + e4[3]) + e4[4]);
        float an = ft + m + __logf(sum);
        ap[(size_t)t * C_ + lane] = an;
        aw[lane] = an;
      }
      if (stv && (t + 2 < T_)) {                    // write row t+2 (loaded last step)
        *(float4*)&gl[(t + 2) & 3][p0] = rA0;
        *(float4*)&gl[(t + 2) & 3][p0 + 4] = rA1;
      }
      rA0 = rB0; rA1 = rB1;
    }
  } else {
    // ---------------- beta ----------------
    int b = wg - B_;
    const float* fp = f + (size_t)b * T_ * C_;
    const float* gp = g + (size_t)b * T_ * C_ * C_;
    float* bp = beta + (size_t)b * T_ * C_;
    if (lane < C_) {
      bp[(size_t)(T_ - 1) * C_ + lane] = 0.f;
      aw[lane] = fp[(size_t)(T_ - 1) * C_ + lane];  // w = f[T-1] + 0
    }
    if (stv) {
      float4 v0 = *(const float4*)(gp + (size_t)(T_ - 1) * 400 + p0);
      float4 v1 = *(const float4*)(gp + (size_t)(T_ - 1) * 400 + p0 + 4);
      *(float4*)&gl[(T_ - 1) & 3][p0] = v0;  *(float4*)&gl[(T_ - 1) & 3][p0 + 4] = v1;
      v0 = *(const float4*)(gp + (size_t)(T_ - 2) * 400 + p0);
      v1 = *(const float4*)(gp + (size_t)(T_ - 2) * 400 + p0 + 4);
      *(float4*)&gl[(T_ - 2) & 3][p0] = v0;  *(float4*)&gl[(T_ - 2) & 3][p0 + 4] = v1;
      rA0 = *(const float4*)(gp + (size_t)(T_ - 3) * 400 + p0);   // row T-3 in flight
      rA1 = *(const float4*)(gp + (size_t)(T_ - 3) * 400 + p0 + 4);
    }
    for (int u = 1; u < T_; ++u) {
      int t = T_ - 1 - u;          // computing beta[t]
      int r = t + 1;               // uses g row r
      if (stv && (r - 3 >= 1)) {   // issue loads for row r-3
        rB0 = *(const float4*)(gp + (size_t)(r - 3) * 400 + p0);
        rB1 = *(const float4*)(gp + (size_t)(r - 3) * 400 + p0 + 4);
      }
      if (lane < C_) {
        const float* gr = &gl[r & 3][lane * 20];
        float fcur = fp[(size_t)t * C_ + lane];
        float awv[20];
        #pragma unroll
        for (int q = 0; q < 5; ++q)
          *(f32x4v*)&awv[4 * q] = ((const f32x4v*)aw)[q];
        float s[20];
        #pragma unroll
        for (int q = 0; q < 5; ++q) {
          f32x4v gq = *(const f32x4v*)&gr[4 * q];   // per-lane b128, stride 80B
          s[4*q]   = awv[4*q]   + gq[0];
          s[4*q+1] = awv[4*q+1] + gq[1];
          s[4*q+2] = awv[4*q+2] + gq[2];
          s[4*q+3] = awv[4*q+3] + gq[3];
        }
        float m4[5];
        #pragma unroll
        for (int q = 0; q < 5; ++q)
          m4[q] = fmaxf(fmaxf(s[4*q], s[4*q+1]), fmaxf(s[4*q+2], s[4*q+3]));
        float m = fmaxf(fmaxf(m4[0], m4[1]), fmaxf(fmaxf(m4[2], m4[3]), m4[4]));
        float e4[5];
        #pragma unroll
        for (int q = 0; q < 5; ++q) {
          float e0 = __expf(s[4*q] - m),   e1 = __expf(s[4*q+1] - m);
          float e2 = __expf(s[4*q+2] - m), e3 = __expf(s[4*q+3] - m);
          e4[q] = (e0 + e1) + (e2 + e3);
        }
        float sum = (e4[0] + e4[1]) + ((e4[2] + e4[3]) + e4[4]);
        float bn = m + __logf(sum);
        bp[(size_t)t * C_ + lane] = bn;
        aw[lane] = fcur + bn;      // w for next step
      }
      if (stv && (r - 2 >= 1)) {   // write row r-2 (loaded last step)
        *(float4*)&gl[(r - 2) & 3][p0] = rA0;
        *(float4*)&gl[(r - 2) & 3][p0 + 4] = rA1;
      }
      rA0 = rB0; rA1 = rB1;
    }
  }
}

// ---------------- logZ per batch ----------------
__global__ void logz_k(const float* __restrict__ alpha, float* __restrict__ lz) {
  int b = blockIdx.x; int lane = threadIdx.x;
  float a = (lane < C_) ? alpha[((size_t)b * T_ + (T_ - 1)) * C_ + lane] : -3.0e38f;
  float m = a;
  #pragma unroll
  for (int o = 32; o > 0; o >>= 1) m = fmaxf(m, __shfl_xor(m, o));
  float e = (lane < C_) ? __expf(a - m) : 0.f;
  #pragma unroll
  for (int o = 32; o > 0; o >>= 1) e += __shfl_xor(e, o);
  if (lane == 0) lz[b] = m + __logf(e);
}

// ---------------- marginals = exp(alpha+beta-logZ) ----------------
__global__ void marg_k(const float* __restrict__ alpha, const float* __restrict__ beta,
                       const float* __restrict__ lz, float* __restrict__ out0) {
  size_t idx = (size_t)blockIdx.x * 256 + threadIdx.x;
  int b = (int)(idx / (T_ * C_));
  out0[idx] = __expf(alpha[idx] + beta[idx] - lz[b]);
}

extern "C" void kernel_launch(void* const* d_in, const int* in_sizes, int n_in,
                              void* d_out, int out_size, void* d_ws, size_t ws_size,
                              hipStream_t stream) {
  const int*   tok   = (const int*)d_in[0];
  const int*   seq   = (const int*)d_in[1];
  const float* emb   = (const float*)d_in[2];
  const float* Wih0  = (const float*)d_in[3];
  const float* Whh0  = (const float*)d_in[4];
  const float* bih0  = (const float*)d_in[5];
  const float* bhh0  = (const float*)d_in[6];
  const float* Wih0r = (const float*)d_in[7];
  const float* Whh0r = (const float*)d_in[8];
  const float* bih0r = (const float*)d_in[9];
  const float* bhh0r = (const float*)d_in[10];
  const float* Wih1  = (const float*)d_in[11];
  const float* Whh1  = (const float*)d_in[12];
  const float* bih1  = (const float*)d_in[13];
  const float* bhh1  = (const float*)d_in[14];
  const float* Wih1r = (const float*)d_in[15];
  const float* Whh1r = (const float*)d_in[16];
  const float* bih1r = (const float*)d_in[17];
  const float* bhh1r = (const float*)d_in[18];
  const float* fW    = (const float*)d_in[19];
  const float* fb    = (const float*)d_in[20];
  const float* gW    = (const float*)d_in[21];
  const float* gb    = (const float*)d_in[22];
  const float* h0    = (const float*)d_in[23];
  const float* c0    = (const float*)d_in[24];

  float* ws = (float*)d_ws;
  float* x0  = ws;                          // 4,194,304 floats
  u16*   xp  = (u16*)(ws + 4194304);        // 104,857,600 bf16
  u16*   x1  = (u16*)(ws + 109051904);      // 26,214,400 bf16
  float* lz  = ws + 135266304;              // 128 floats

  float* out   = (float*)d_out;
  float* f_out = out + 2621440;
  float* g_out = out + 5242880;
  float* a_out = out + 57671680;
  float* b_out = out + 60293120;

  embed_k<<<16384, 256, 0, stream>>>(tok, emb, x0);

  dim3 g400(2048, 7), g20(2048, 1);
  // layer 0 input projections (K=32): fp32 A -> bf16 xp
  gemm_mfma_t<0,1><<<g400, 256, 0, stream>>>(x0, Wih0,  bih0,  bhh0,  xp,                    32, 400, 400);
  gemm_mfma_t<0,1><<<g400, 256, 0, stream>>>(x0, Wih0r, bih0r, bhh0r, xp + (size_t)52428800, 32, 400, 400);
  lstm_scan<<<256, 256, 0, stream>>>(xp, Whh0, Whh0r, h0, c0, nullptr, x1, 0);
  // layer 1 input projections (K=200): bf16 A -> bf16 xp
  gemm_mfma_t<1,1><<<g400, 256, 0, stream>>>(x1, Wih1,  bih1,  bhh1,  xp,                    200, 400, 400);
  gemm_mfma_t<1,1><<<g400, 256, 0, stream>>>(x1, Wih1r, bih1r, bhh1r, xp + (size_t)52428800, 200, 400, 400);
  lstm_scan<<<256, 256, 0, stream>>>(xp, Whh1, Whh1r, h0, c0, seq, x1, 1);
  // emissions + transitions: bf16 A -> fp32 outputs
  gemm_mfma_t<1,0><<<g20,  256, 0, stream>>>(x1, fW, fb, nullptr, f_out, 200, 20,  20);
  gemm_mfma_t<1,0><<<g400, 256, 0, stream>>>(x1, gW, gb, nullptr, g_out, 200, 400, 400);
  // CRF forward/backward
  crf_k<<<256, 64, 0, stream>>>(f_out, g_out, a_out, b_out);
  logz_k<<<128, 64, 0, stream>>>(a_out, lz);
  marg_k<<<10240, 256, 0, stream>>>(a_out, b_out, lz, out);
}

// Round 16
// 2734.409 us; speedup vs baseline: 1.6798x; 1.0016x over previous
//
#include <hip/hip_runtime.h>
#include <hip/hip_bf16.h>

#define B_ 128
#define T_ 1024
#define E_ 32
#define H_ 100
#define C_ 20
#define M_ (B_*T_)   // 131072

typedef __attribute__((ext_vector_type(8))) short bf16x8v;
typedef __attribute__((ext_vector_type(4))) float f32x4v;
typedef __attribute__((ext_vector_type(2))) _Float16 h2v;
typedef unsigned short u16;
typedef unsigned int u32;

static __device__ __forceinline__ short f2b(float x) {
  union { __hip_bfloat16 b; short s; } u;
  u.b = __float2bfloat16(x);
  return u.s;
}
static __device__ __forceinline__ float b2f(u16 x) {
  return __uint_as_float(((u32)x) << 16);
}

#if __has_builtin(__builtin_amdgcn_fdot2)
#define FDOT2(w, p, c) __builtin_amdgcn_fdot2((w), (p), (c), false)
#else
static __device__ __forceinline__ float FDOT2(h2v w, h2v p, float c) {
  return fmaf((float)w[1], (float)p[1], fmaf((float)w[0], (float)p[0], c));
}
#endif

// ---------------- embedding lookup ----------------
__global__ void embed_k(const int* __restrict__ tok, const float* __restrict__ emb,
                        float* __restrict__ x0) {
  int idx = blockIdx.x * 256 + threadIdx.x;   // over M_*E_ = 4194304
  int bt = idx >> 5;
  int e  = idx & 31;
  x0[idx] = emb[tok[bt] * E_ + e];
}

// ---------------- bf16 MFMA GEMM: C[M,N] = A[M,K] @ W[N,K]^T + b1 + b2 ------
template<int ABF, int OBF>
__global__ __launch_bounds__(256) void gemm_mfma_t(
    const void* __restrict__ Av, const float* __restrict__ W,
    const float* __restrict__ b1, const float* __restrict__ b2,
    void* __restrict__ Cv, int K, int N, int ldc)
{
  __shared__ short as[64 * 40];   // [row][k] pad 40
  __shared__ short ws[64 * 40];   // [col][k]
  const float* Af = (const float*)Av;
  const u16*   Ab = (const u16*)Av;
  float* Cf = (float*)Cv;
  u16*   Cb = (u16*)Cv;
  int tid = threadIdx.x, lane = tid & 63, w = tid >> 6;
  int lr = lane & 15, lq = lane >> 4;
  size_t m0 = (size_t)blockIdx.x * 64;
  int n0 = blockIdx.y * 64;
  int srow = tid >> 2;            // staging row 0..63
  int sk = (tid & 3) * 8;         // staging k offset 0,8,16,24
  bool wok = (n0 + srow) < N;
  const float* Wp = wok ? (W + (size_t)(n0 + srow) * K + sk) : W;
  size_t arow = (m0 + srow) * (size_t)K;
  f32x4v acc[4];
  #pragma unroll
  for (int r = 0; r < 4; ++r) acc[r] = (f32x4v){0.f, 0.f, 0.f, 0.f};
  int ksteps = (K + 31) / 32;
  for (int ks = 0; ks < ksteps; ++ks) {
    int kk = ks * 32;
    bf16x8v av, wv;
    if (kk + sk + 7 < K) {
      if (ABF) {
        av = *(const bf16x8v*)(Ab + arow + kk + sk);
      } else {
        float4 a0 = *(const float4*)(Af + arow + kk + sk);
        float4 a1 = *(const float4*)(Af + arow + kk + sk + 4);
        av[0]=f2b(a0.x); av[1]=f2b(a0.y); av[2]=f2b(a0.z); av[3]=f2b(a0.w);
        av[4]=f2b(a1.x); av[5]=f2b(a1.y); av[6]=f2b(a1.z); av[7]=f2b(a1.w);
      }
      if (wok) {
        float4 w0 = *(const float4*)(Wp + kk);
        float4 w1 = *(const float4*)(Wp + kk + 4);
        wv[0]=f2b(w0.x); wv[1]=f2b(w0.y); wv[2]=f2b(w0.z); wv[3]=f2b(w0.w);
        wv[4]=f2b(w1.x); wv[5]=f2b(w1.y); wv[6]=f2b(w1.z); wv[7]=f2b(w1.w);
      } else {
        #pragma unroll
        for (int j = 0; j < 8; ++j) wv[j] = 0;
      }
    } else {
      #pragma unroll
      for (int j = 0; j < 8; ++j) {
        int k = kk + sk + j;
        av[j] = (k < K) ? (ABF ? (short)Ab[arow + k] : f2b(Af[arow + k])) : (short)0;
        wv[j] = (wok && k < K) ? f2b(W[(size_t)(n0 + srow) * K + k]) : (short)0;
      }
    }
    *(bf16x8v*)&as[srow * 40 + sk] = av;
    *(bf16x8v*)&ws[srow * 40 + sk] = wv;
    __syncthreads();
    bf16x8v bf = *(const bf16x8v*)&ws[(16 * w + lr) * 40 + 8 * lq];
    #pragma unroll
    for (int r = 0; r < 4; ++r) {
      bf16x8v af = *(const bf16x8v*)&as[(16 * r + lr) * 40 + 8 * lq];
      acc[r] = __builtin_amdgcn_mfma_f32_16x16x32_bf16(af, bf, acc[r], 0, 0, 0);
    }
    __syncthreads();
  }
  int col = n0 + 16 * w + lr;
  if (col < N) {
    float bv = (b1 ? b1[col] : 0.f) + (b2 ? b2[col] : 0.f);
    #pragma unroll
    for (int r = 0; r < 4; ++r)
      #pragma unroll
      for (int rg = 0; rg < 4; ++rg) {
        size_t off = (m0 + 16 * r + 4 * lq + rg) * (size_t)ldc + col;
        float v = acc[r][rg] + bv;
        if (OBF) Cb[off] = (u16)f2b(v); else Cf[off] = v;
      }
  }
}

// Pin a float4's components into VGPRs (blocks rematerialization of the load).
#define PIN4(v) asm volatile("" : "+v"((v).x), "+v"((v).y), "+v"((v).z), "+v"((v).w))

// ---------------- LSTM scan, f16-packed FLOAT4-typed register weights -------
// r15 post-mortem: 104 scalar u32 pins -> grant 84, ~50 spilled (857us).
// r13 evidence: 25 PIN4'd float4 (100 regs) -> grant 140, fully resident.
// Theory: AMDGPU RA allocates vector-typed (64b-aligned tuple) live ranges
// coherently but fragments on 100+ independent scalar vregs. Single change:
// retype the f16-packed weights as float4 w0q[13]/w1q[13] (same 104 VGPRs of
// payload, same h2v packing per 32-bit lane), PIN4'd; bit-cast at FDOT2 site.
__global__ __launch_bounds__(256, 1) void lstm_scan(
    const u16* __restrict__ xp,
    const float* __restrict__ WhhF, const float* __restrict__ WhhR,
    const float* __restrict__ h0, const float* __restrict__ c0, // [4][B][H]
    const int* __restrict__ seqlen,   // null => no mask
    u16* __restrict__ outbuf,         // [B][T][200] bf16, dir*100 offset
    int layer)
{
  int wg = blockIdx.x; int dir = wg & 1; int b = wg >> 1;
  int tid = threadIdx.x;
  const float* Whh = dir ? WhhR : WhhF;
  const u16* xpp = xp + ((size_t)dir * B_ + b) * T_ * 400;
  const float* h0p = h0 + ((size_t)(2 * layer + dir) * B_ + b) * H_;
  const float* c0p = c0 + ((size_t)(2 * layer + dir) * B_ + b) * H_;
  __shared__ __align__(16) float gsh[400];
  __shared__ __align__(16) _Float16 hph[112];   // h as f16; [100..111] = 0
  bool act = (tid < 200);
  float4 w0q[13], w1q[13];
  if (act) {
    const float* r0 = Whh + (size_t)(2 * tid) * H_;
    const float* r1 = Whh + (size_t)(2 * tid + 1) * H_;
    #pragma unroll
    for (int q = 0; q < 13; ++q) {
      float c0f[4], c1f[4];
      #pragma unroll
      for (int i = 0; i < 4; ++i) {
        int k = 8 * q + 2 * i;
        float a0 = (k < 100) ? r0[k] : 0.f;
        float a1 = (k + 1 < 100) ? r0[k + 1] : 0.f;
        float b0 = (k < 100) ? r1[k] : 0.f;
        float b1 = (k + 1 < 100) ? r1[k + 1] : 0.f;
        c0f[i] = __builtin_bit_cast(float, (h2v){(_Float16)a0, (_Float16)a1});
        c1f[i] = __builtin_bit_cast(float, (h2v){(_Float16)b0, (_Float16)b1});
      }
      w0q[q] = make_float4(c0f[0], c0f[1], c0f[2], c0f[3]);
      w1q[q] = make_float4(c1f[0], c1f[1], c1f[2], c1f[3]);
    }
    #pragma unroll
    for (int q = 0; q < 13; ++q) { PIN4(w0q[q]); PIN4(w1q[q]); }
  }
  if (tid < 112) hph[tid] = (_Float16)((tid < H_) ? h0p[tid] : 0.f);
  float c = (tid < H_) ? c0p[tid] : 0.f;
  int sl = seqlen ? seqlen[b] : T_;
  __syncthreads();
  int tstep = dir ? -1 : 1;
  int t0 = dir ? (T_ - 1) : 0;
  ushort2 xc = make_ushort2(0, 0), xn = make_ushort2(0, 0);
  if (act) {
    xc = *(const ushort2*)(xpp + (size_t)t0 * 400 + 2 * tid);
    xn = *(const ushort2*)(xpp + (size_t)(t0 + tstep) * 400 + 2 * tid);
  }
  for (int tt = 0; tt < T_; ++tt) {
    int t = t0 + tstep * tt;
    ushort2 xn2 = make_ushort2(0, 0);
    if (act && tt + 2 < T_)
      xn2 = *(const ushort2*)(xpp + (size_t)(t + 2 * tstep) * 400 + 2 * tid);
    if (act) {
      float a0 = b2f(xc.x), a1 = b2f(xc.y);
      #pragma unroll
      for (int q = 0; q < 13; ++q) {
        f32x4v hp = ((const f32x4v*)hph)[q];   // uniform addr -> broadcast
        h2v p0 = __builtin_bit_cast(h2v, hp[0]);
        h2v p1 = __builtin_bit_cast(h2v, hp[1]);
        h2v p2 = __builtin_bit_cast(h2v, hp[2]);
        h2v p3 = __builtin_bit_cast(h2v, hp[3]);
        a0 = FDOT2(__builtin_bit_cast(h2v, w0q[q].x), p0, a0);
        a1 = FDOT2(__builtin_bit_cast(h2v, w1q[q].x), p0, a1);
        a0 = FDOT2(__builtin_bit_cast(h2v, w0q[q].y), p1, a0);
        a1 = FDOT2(__builtin_bit_cast(h2v, w1q[q].y), p1, a1);
        a0 = FDOT2(__builtin_bit_cast(h2v, w0q[q].z), p2, a0);
        a1 = FDOT2(__builtin_bit_cast(h2v, w1q[q].z), p2, a1);
        a0 = FDOT2(__builtin_bit_cast(h2v, w0q[q].w), p3, a0);
        a1 = FDOT2(__builtin_bit_cast(h2v, w1q[q].w), p3, a1);
      }
      *(float2*)&gsh[2 * tid] = make_float2(a0, a1);
    }
    __syncthreads();
    if (tid < H_) {
      float gi = gsh[tid], gf = gsh[H_ + tid], gg = gsh[2 * H_ + tid], go = gsh[3 * H_ + tid];
      float si = 1.f / (1.f + __expf(-gi));
      float sf = 1.f / (1.f + __expf(-gf));
      float so = 1.f / (1.f + __expf(-go));
      float tg = 1.f - 2.f / (1.f + __expf(2.f * gg));
      c = fmaf(sf, c, si * tg);
      float tc = 1.f - 2.f / (1.f + __expf(2.f * c));
      float h = so * tc;
      hph[tid] = (_Float16)h;
      outbuf[((size_t)b * T_ + t) * 200 + dir * H_ + tid] = (t < sl) ? (u16)f2b(h) : (u16)0;
    }
    __syncthreads();
    xc = xn; xn = xn2;
  }
}

// ---------------- CRF with LDS ring staging (r15 winner, unchanged) --------
__global__ __launch_bounds__(64) void crf_k(
    const float* __restrict__ f, const float* __restrict__ g,
    float* __restrict__ alpha, float* __restrict__ beta)
{
  int wg = blockIdx.x;
  int lane = threadIdx.x;
  __shared__ __align__(16) float gl[4][400];   // ring: row r -> slot r&3
  __shared__ __align__(16) float aw[20];       // alpha: a[t-1]; beta: f[t+1]+b[t+1]
  bool stv = lane < 50;
  int p0 = 8 * lane;                           // this lane stages floats [p0,p0+8)
  float4 rA0, rA1, rB0, rB1;                   // in-flight staged row (reg ring)

  if (wg < B_) {
    // ---------------- alpha ----------------
    int b = wg;
    const float* fp = f + (size_t)b * T_ * C_;
    const float* gp = g + (size_t)b * T_ * C_ * C_;
    float* ap = alpha + (size_t)b * T_ * C_;
    if (lane < C_) {
      float a0 = fp[lane];
      ap[lane] = a0;
      aw[lane] = a0;
    }
    if (stv) {
      float4 v0 = *(const float4*)(gp + 400 + p0);
      float4 v1 = *(const float4*)(gp + 404 + p0);
      *(float4*)&gl[1 & 3][p0] = v0;  *(float4*)&gl[1 & 3][p0 + 4] = v1;
      v0 = *(const float4*)(gp + 800 + p0);
      v1 = *(const float4*)(gp + 804 + p0);
      *(float4*)&gl[2 & 3][p0] = v0;  *(float4*)&gl[2 & 3][p0 + 4] = v1;
      rA0 = *(const float4*)(gp + 1200 + p0);       // row 3 in flight
      rA1 = *(const float4*)(gp + 1204 + p0);
    }
    for (int t = 1; t < T_; ++t) {
      if (stv && (t + 3 < T_)) {                    // issue loads for row t+3
        rB0 = *(const float4*)(gp + (size_t)(t + 3) * 400 + p0);
        rB1 = *(const float4*)(gp + (size_t)(t + 3) * 400 + p0 + 4);
      }
      if (lane < C_) {
        const float* gr = &gl[t & 3][0];
        float ft = fp[(size_t)t * C_ + lane];       // issued early, used late
        float awv[20];
        #pragma unroll
        for (int q = 0; q < 5; ++q)
          *(f32x4v*)&awv[4 * q] = ((const f32x4v*)aw)[q];   // uniform b128
        float s[20];
        #pragma unroll
        for (int i = 0; i < 20; ++i)
          s[i] = awv[i] + gr[i * 20 + lane];        // consecutive -> no conflict
        float m4[5];
        #pragma unroll
        for (int q = 0; q < 5; ++q)
          m4[q] = fmaxf(fmaxf(s[4*q], s[4*q+1]), fmaxf(s[4*q+2], s[4*q+3]));
        float m = fmaxf(fmaxf(m4[0], m4[1]), fmaxf(fmaxf(m4[2], m4[3]), m4[4]));
        float e4[5];
        #pragma unroll
        for (int q = 0; q < 5; ++q) {
          float e0 = __expf(s[4*q] - m),   e1 = __expf(s[4*q+1] - m);
          float e2 = __expf(s[4*q+2] - m), e3 = __expf(s[4*q+3] - m);
          e4[q] = (e0 + e1) + (e2 + e3);
        }
        float sum = (e4[0] + e4[1]) + ((e4[2] + e4[3]) + e4[4]);
        float an = ft + m + __logf(sum);
        ap[(size_t)t * C_ + lane] = an;
        aw[lane] = an;
      }
      if (stv && (t + 2 < T_)) {                    // write row t+2 (loaded last step)
        *(float4*)&gl[(t + 2) & 3][p0] = rA0;
        *(float4*)&gl[(t + 2) & 3][p0 + 4] = rA1;
      }
      rA0 = rB0; rA1 = rB1;
    }
  } else {
    // ---------------- beta ----------------
    int b = wg - B_;
    const float* fp = f + (size_t)b * T_ * C_;
    const float* gp = g + (size_t)b * T_ * C_ * C_;
    float* bp = beta + (size_t)b * T_ * C_;
    if (lane < C_) {
      bp[(size_t)(T_ - 1) * C_ + lane] = 0.f;
      aw[lane] = fp[(size_t)(T_ - 1) * C_ + lane];  // w = f[T-1] + 0
    }
    if (stv) {
      float4 v0 = *(const float4*)(gp + (size_t)(T_ - 1) * 400 + p0);
      float4 v1 = *(const float4*)(gp + (size_t)(T_ - 1) * 400 + p0 + 4);
      *(float4*)&gl[(T_ - 1) & 3][p0] = v0;  *(float4*)&gl[(T_ - 1) & 3][p0 + 4] = v1;
      v0 = *(const float4*)(gp + (size_t)(T_ - 2) * 400 + p0);
      v1 = *(const float4*)(gp + (size_t)(T_ - 2) * 400 + p0 + 4);
      *(float4*)&gl[(T_ - 2) & 3][p0] = v0;  *(float4*)&gl[(T_ - 2) & 3][p0 + 4] = v1;
      rA0 = *(const float4*)(gp + (size_t)(T_ - 3) * 400 + p0);   // row T-3 in flight
      rA1 = *(const float4*)(gp + (size_t)(T_ - 3) * 400 + p0 + 4);
    }
    for (int u = 1; u < T_; ++u) {
      int t = T_ - 1 - u;          // computing beta[t]
      int r = t + 1;               // uses g row r
      if (stv && (r - 3 >= 1)) {   // issue loads for row r-3
        rB0 = *(const float4*)(gp + (size_t)(r - 3) * 400 + p0);
        rB1 = *(const float4*)(gp + (size_t)(r - 3) * 400 + p0 + 4);
      }
      if (lane < C_) {
        const float* gr = &gl[r & 3][lane * 20];
        float fcur = fp[(size_t)t * C_ + lane];
        float awv[20];
        #pragma unroll
        for (int q = 0; q < 5; ++q)
          *(f32x4v*)&awv[4 * q] = ((const f32x4v*)aw)[q];
        float s[20];
        #pragma unroll
        for (int q = 0; q < 5; ++q) {
          f32x4v gq = *(const f32x4v*)&gr[4 * q];   // per-lane b128, stride 80B
          s[4*q]   = awv[4*q]   + gq[0];
          s[4*q+1] = awv[4*q+1] + gq[1];
          s[4*q+2] = awv[4*q+2] + gq[2];
          s[4*q+3] = awv[4*q+3] + gq[3];
        }
        float m4[5];
        #pragma unroll
        for (int q = 0; q < 5; ++q)
          m4[q] = fmaxf(fmaxf(s[4*q], s[4*q+1]), fmaxf(s[4*q+2], s[4*q+3]));
        float m = fmaxf(fmaxf(m4[0], m4[1]), fmaxf(fmaxf(m4[2], m4[3]), m4[4]));
        float e4[5];
        #pragma unroll
        for (int q = 0; q < 5; ++q) {
          float e0 = __expf(s[4*q] - m),   e1 = __expf(s[4*q+1] - m);
          float e2 = __expf(s[4*q+2] - m), e3 = __expf(s[4*q+3] - m);
          e4[q] = (e0 + e1) + (e2 + e3);
        }
        float sum = (e4[0] + e4[1]) + ((e4[2] + e4[3]) + e4[4]);
        float bn = m + __logf(sum);
        bp[(size_t)t * C_ + lane] = bn;
        aw[lane] = fcur + bn;      // w for next step
      }
      if (stv && (r - 2 >= 1)) {   // write row r-2 (loaded last step)
        *(float4*)&gl[(r - 2) & 3][p0] = rA0;
        *(float4*)&gl[(r - 2) & 3][p0 + 4] = rA1;
      }
      rA0 = rB0; rA1 = rB1;
    }
  }
}

// ---------------- logZ per batch ----------------
__global__ void logz_k(const float* __restrict__ alpha, float* __restrict__ lz) {
  int b = blockIdx.x; int lane = threadIdx.x;
  float a = (lane < C_) ? alpha[((size_t)b * T_ + (T_ - 1)) * C_ + lane] : -3.0e38f;
  float m = a;
  #pragma unroll
  for (int o = 32; o > 0; o >>= 1) m = fmaxf(m, __shfl_xor(m, o));
  float e = (lane < C_) ? __expf(a - m) : 0.f;
  #pragma unroll
  for (int o = 32; o > 0; o >>= 1) e += __shfl_xor(e, o);
  if (lane == 0) lz[b] = m + __logf(e);
}

// ---------------- marginals = exp(alpha+beta-logZ) ----------------
__global__ void marg_k(const float* __restrict__ alpha, const float* __restrict__ beta,
                       const float* __restrict__ lz, float* __restrict__ out0) {
  size_t idx = (size_t)blockIdx.x * 256 + threadIdx.x;
  int b = (int)(idx / (T_ * C_));
  out0[idx] = __expf(alpha[idx] + beta[idx] - lz[b]);
}

extern "C" void kernel_launch(void* const* d_in, const int* in_sizes, int n_in,
                              void* d_out, int out_size, void* d_ws, size_t ws_size,
                              hipStream_t stream) {
  const int*   tok   = (const int*)d_in[0];
  const int*   seq   = (const int*)d_in[1];
  const float* emb   = (const float*)d_in[2];
  const float* Wih0  = (const float*)d_in[3];
  const float* Whh0  = (const float*)d_in[4];
  const float* bih0  = (const float*)d_in[5];
  const float* bhh0  = (const float*)d_in[6];
  const float* Wih0r = (const float*)d_in[7];
  const float* Whh0r = (const float*)d_in[8];
  const float* bih0r = (const float*)d_in[9];
  const float* bhh0r = (const float*)d_in[10];
  const float* Wih1  = (const float*)d_in[11];
  const float* Whh1  = (const float*)d_in[12];
  const float* bih1  = (const float*)d_in[13];
  const float* bhh1  = (const float*)d_in[14];
  const float* Wih1r = (const float*)d_in[15];
  const float* Whh1r = (const float*)d_in[16];
  const float* bih1r = (const float*)d_in[17];
  const float* bhh1r = (const float*)d_in[18];
  const float* fW    = (const float*)d_in[19];
  const float* fb    = (const float*)d_in[20];
  const float* gW    = (const float*)d_in[21];
  const float* gb    = (const float*)d_in[22];
  const float* h0    = (const float*)d_in[23];
  const float* c0    = (const float*)d_in[24];

  float* ws = (float*)d_ws;
  float* x0  = ws;                          // 4,194,304 floats
  u16*   xp  = (u16*)(ws + 4194304);        // 104,857,600 bf16
  u16*   x1  = (u16*)(ws + 109051904);      // 26,214,400 bf16
  float* lz  = ws + 135266304;              // 128 floats

  float* out   = (float*)d_out;
  float* f_out = out + 2621440;
  float* g_out = out + 5242880;
  float* a_out = out + 57671680;
  float* b_out = out + 60293120;

  embed_k<<<16384, 256, 0, stream>>>(tok, emb, x0);

  dim3 g400(2048, 7), g20(2048, 1);
  // layer 0 input projections (K=32): fp32 A -> bf16 xp
  gemm_mfma_t<0,1><<<g400, 256, 0, stream>>>(x0, Wih0,  bih0,  bhh0,  xp,                    32, 400, 400);
  gemm_mfma_t<0,1><<<g400, 256, 0, stream>>>(x0, Wih0r, bih0r, bhh0r, xp + (size_t)52428800, 32, 400, 400);
  lstm_scan<<<256, 256, 0, stream>>>(xp, Whh0, Whh0r, h0, c0, nullptr, x1, 0);
  // layer 1 input projections (K=200): bf16 A -> bf16 xp
  gemm_mfma_t<1,1><<<g400, 256, 0, stream>>>(x1, Wih1,  bih1,  bhh1,  xp,                    200, 400, 400);
  gemm_mfma_t<1,1><<<g400, 256, 0, stream>>>(x1, Wih1r, bih1r, bhh1r, xp + (size_t)52428800, 200, 400, 400);
  lstm_scan<<<256, 256, 0, stream>>>(xp, Whh1, Whh1r, h0, c0, seq, x1, 1);
  // emissions + transitions: bf16 A -> fp32 outputs
  gemm_mfma_t<1,0><<<g20,  256, 0, stream>>>(x1, fW, fb, nullptr, f_out, 200, 20,  20);
  gemm_mfma_t<1,0><<<g400, 256, 0, stream>>>(x1, gW, gb, nullptr, g_out, 200, 400, 400);
  // CRF forward/backward
  crf_k<<<256, 64, 0, stream>>>(f_out, g_out, a_out, b_out);
  logz_k<<<128, 64, 0, stream>>>(a_out, lz);
  marg_k<<<10240, 256, 0, stream>>>(a_out, b_out, lz, out);
}

// Round 17
// 2679.761 us; speedup vs baseline: 1.7141x; 1.0204x over previous
//
#include <hip/hip_runtime.h>
#include <hip/hip_bf16.h>

#define B_ 128
#define T_ 1024
#define E_ 32
#define H_ 100
#define C_ 20
#define M_ (B_*T_)   // 131072

typedef __attribute__((ext_vector_type(8))) short bf16x8v;
typedef __attribute__((ext_vector_type(4))) float f32x4v;
typedef __attribute__((ext_vector_type(2))) _Float16 h2v;
typedef unsigned short u16;
typedef unsigned int u32;

static __device__ __forceinline__ short f2b(float x) {
  union { __hip_bfloat16 b; short s; } u;
  u.b = __float2bfloat16(x);
  return u.s;
}
static __device__ __forceinline__ float b2f(u16 x) {
  return __uint_as_float(((u32)x) << 16);
}

#if __has_builtin(__builtin_amdgcn_fdot2)
#define FDOT2(w, p, c) __builtin_amdgcn_fdot2((w), (p), (c), false)
#else
static __device__ __forceinline__ float FDOT2(h2v w, h2v p, float c) {
  return fmaf((float)w[1], (float)p[1], fmaf((float)w[0], (float)p[0], c));
}
#endif

// ---------------- embedding lookup ----------------
__global__ void embed_k(const int* __restrict__ tok, const float* __restrict__ emb,
                        float* __restrict__ x0) {
  int idx = blockIdx.x * 256 + threadIdx.x;   // over M_*E_ = 4194304
  int bt = idx >> 5;
  int e  = idx & 31;
  x0[idx] = emb[tok[bt] * E_ + e];
}

// ---------------- bf16 MFMA GEMM: C[M,N] = A[M,K] @ W[N,K]^T + b1 + b2 ------
template<int ABF, int OBF>
__global__ __launch_bounds__(256) void gemm_mfma_t(
    const void* __restrict__ Av, const float* __restrict__ W,
    const float* __restrict__ b1, const float* __restrict__ b2,
    void* __restrict__ Cv, int K, int N, int ldc)
{
  __shared__ short as[64 * 40];   // [row][k] pad 40
  __shared__ short ws[64 * 40];   // [col][k]
  const float* Af = (const float*)Av;
  const u16*   Ab = (const u16*)Av;
  float* Cf = (float*)Cv;
  u16*   Cb = (u16*)Cv;
  int tid = threadIdx.x, lane = tid & 63, w = tid >> 6;
  int lr = lane & 15, lq = lane >> 4;
  size_t m0 = (size_t)blockIdx.x * 64;
  int n0 = blockIdx.y * 64;
  int srow = tid >> 2;            // staging row 0..63
  int sk = (tid & 3) * 8;         // staging k offset 0,8,16,24
  bool wok = (n0 + srow) < N;
  const float* Wp = wok ? (W + (size_t)(n0 + srow) * K + sk) : W;
  size_t arow = (m0 + srow) * (size_t)K;
  f32x4v acc[4];
  #pragma unroll
  for (int r = 0; r < 4; ++r) acc[r] = (f32x4v){0.f, 0.f, 0.f, 0.f};
  int ksteps = (K + 31) / 32;
  for (int ks = 0; ks < ksteps; ++ks) {
    int kk = ks * 32;
    bf16x8v av, wv;
    if (kk + sk + 7 < K) {
      if (ABF) {
        av = *(const bf16x8v*)(Ab + arow + kk + sk);
      } else {
        float4 a0 = *(const float4*)(Af + arow + kk + sk);
        float4 a1 = *(const float4*)(Af + arow + kk + sk + 4);
        av[0]=f2b(a0.x); av[1]=f2b(a0.y); av[2]=f2b(a0.z); av[3]=f2b(a0.w);
        av[4]=f2b(a1.x); av[5]=f2b(a1.y); av[6]=f2b(a1.z); av[7]=f2b(a1.w);
      }
      if (wok) {
        float4 w0 = *(const float4*)(Wp + kk);
        float4 w1 = *(const float4*)(Wp + kk + 4);
        wv[0]=f2b(w0.x); wv[1]=f2b(w0.y); wv[2]=f2b(w0.z); wv[3]=f2b(w0.w);
        wv[4]=f2b(w1.x); wv[5]=f2b(w1.y); wv[6]=f2b(w1.z); wv[7]=f2b(w1.w);
      } else {
        #pragma unroll
        for (int j = 0; j < 8; ++j) wv[j] = 0;
      }
    } else {
      #pragma unroll
      for (int j = 0; j < 8; ++j) {
        int k = kk + sk + j;
        av[j] = (k < K) ? (ABF ? (short)Ab[arow + k] : f2b(Af[arow + k])) : (short)0;
        wv[j] = (wok && k < K) ? f2b(W[(size_t)(n0 + srow) * K + k]) : (short)0;
      }
    }
    *(bf16x8v*)&as[srow * 40 + sk] = av;
    *(bf16x8v*)&ws[srow * 40 + sk] = wv;
    __syncthreads();
    bf16x8v bf = *(const bf16x8v*)&ws[(16 * w + lr) * 40 + 8 * lq];
    #pragma unroll
    for (int r = 0; r < 4; ++r) {
      bf16x8v af = *(const bf16x8v*)&as[(16 * r + lr) * 40 + 8 * lq];
      acc[r] = __builtin_amdgcn_mfma_f32_16x16x32_bf16(af, bf, acc[r], 0, 0, 0);
    }
    __syncthreads();
  }
  int col = n0 + 16 * w + lr;
  if (col < N) {
    float bv = (b1 ? b1[col] : 0.f) + (b2 ? b2[col] : 0.f);
    #pragma unroll
    for (int r = 0; r < 4; ++r)
      #pragma unroll
      for (int rg = 0; rg < 4; ++rg) {
        size_t off = (m0 + 16 * r + 4 * lq + rg) * (size_t)ldc + col;
        float v = acc[r][rg] + bv;
        if (OBF) Cb[off] = (u16)f2b(v); else Cf[off] = v;
      }
  }
}

// ---------------- LSTM scan, k-split f16-packed register weights ------------
// r16 post-mortem: typing theory falsified (float4 pack -> same 84 grant, same
// 857us). Demand must go BELOW the worst observed grant (84). k-split: 512
// threads; pair (2r,2r+1) owns gate rows 2r/2r+1 with k in [0,48)/[48,100).
// Payload 28 u32/row x 2 = 56 VGPR (+~20 misc = ~76 < 84). Partials combined
// via 2x shfl_xor(.,1) (adjacent lanes, same wave). h: 7x b128 LDS reads, 2
// distinct addrs/wave (2-way broadcast = free, m136). 8 waves = 2/SIMD hides
// the 28-deep dot2 chains.
__global__ __launch_bounds__(512, 1) void lstm_scan(
    const u16* __restrict__ xp,
    const float* __restrict__ WhhF, const float* __restrict__ WhhR,
    const float* __restrict__ h0, const float* __restrict__ c0, // [4][B][H]
    const int* __restrict__ seqlen,   // null => no mask
    u16* __restrict__ outbuf,         // [B][T][200] bf16, dir*100 offset
    int layer)
{
  int wg = blockIdx.x; int dir = wg & 1; int b = wg >> 1;
  int tid = threadIdx.x;
  const float* Whh = dir ? WhhR : WhhF;
  const u16* xpp = xp + ((size_t)dir * B_ + b) * T_ * 400;
  const float* h0p = h0 + ((size_t)(2 * layer + dir) * B_ + b) * H_;
  const float* c0p = c0 + ((size_t)(2 * layer + dir) * B_ + b) * H_;
  __shared__ __align__(16) float gsh[400];
  __shared__ __align__(16) _Float16 hph[112];   // h as f16; [100..111] = 0
  bool act = (tid < 400);
  int r = tid >> 1, half = tid & 1;
  int bu = half * 24;   // base k-pair (u32) index: half0 -> kp 0..23, half1 -> kp 24..49
  u32 w0p[28], w1p[28];
  if (act) {
    const float* r0 = Whh + (size_t)(2 * r) * H_;
    const float* r1 = Whh + (size_t)(2 * r + 1) * H_;
    #pragma unroll
    for (int j = 0; j < 28; ++j) {
      int kp = bu + j;
      bool rl = half ? (j < 26) : (j < 24);   // real (non-overlap, in-range) slot
      int k = 2 * kp;
      float a0 = (rl && k < 100) ? r0[k] : 0.f;
      float a1 = (rl && k + 1 < 100) ? r0[k + 1] : 0.f;
      float b0 = (rl && k < 100) ? r1[k] : 0.f;
      float b1 = (rl && k + 1 < 100) ? r1[k + 1] : 0.f;
      w0p[j] = __builtin_bit_cast(u32, (h2v){(_Float16)a0, (_Float16)a1});
      w1p[j] = __builtin_bit_cast(u32, (h2v){(_Float16)b0, (_Float16)b1});
    }
    #pragma unroll
    for (int j = 0; j < 28; ++j)
      asm volatile("" : "+v"(w0p[j]), "+v"(w1p[j]));
  }
  if (tid < 112) hph[tid] = (_Float16)((tid < H_) ? h0p[tid] : 0.f);
  float c = (tid < H_) ? c0p[tid] : 0.f;
  int sl = seqlen ? seqlen[b] : T_;
  __syncthreads();
  int tstep = dir ? -1 : 1;
  int t0 = dir ? (T_ - 1) : 0;
  ushort2 xc = make_ushort2(0, 0), xn = make_ushort2(0, 0);
  bool ldx = act && !half;
  if (ldx) {
    xc = *(const ushort2*)(xpp + (size_t)t0 * 400 + 2 * r);
    xn = *(const ushort2*)(xpp + (size_t)(t0 + tstep) * 400 + 2 * r);
  }
  for (int tt = 0; tt < T_; ++tt) {
    int t = t0 + tstep * tt;
    ushort2 xn2 = make_ushort2(0, 0);
    if (ldx && tt + 2 < T_)
      xn2 = *(const ushort2*)(xpp + (size_t)(t + 2 * tstep) * 400 + 2 * r);
    if (act) {
      float a0 = half ? 0.f : b2f(xc.x);
      float a1 = half ? 0.f : b2f(xc.y);
      #pragma unroll
      for (int q = 0; q < 7; ++q) {
        f32x4v hp = ((const f32x4v*)hph)[6 * half + q];   // 2 addrs/wave -> free
        #pragma unroll
        for (int i = 0; i < 4; ++i) {
          h2v p = __builtin_bit_cast(h2v, hp[i]);
          a0 = FDOT2(__builtin_bit_cast(h2v, w0p[4 * q + i]), p, a0);
          a1 = FDOT2(__builtin_bit_cast(h2v, w1p[4 * q + i]), p, a1);
        }
      }
      a0 += __shfl_xor(a0, 1);   // combine k-halves (adjacent lanes)
      a1 += __shfl_xor(a1, 1);
      if (!half) *(float2*)&gsh[2 * r] = make_float2(a0, a1);
    }
    __syncthreads();
    if (tid < H_) {
      float gi = gsh[tid], gf = gsh[H_ + tid], gg = gsh[2 * H_ + tid], go = gsh[3 * H_ + tid];
      float si = 1.f / (1.f + __expf(-gi));
      float sf = 1.f / (1.f + __expf(-gf));
      float so = 1.f / (1.f + __expf(-go));
      float tg = 1.f - 2.f / (1.f + __expf(2.f * gg));
      c = fmaf(sf, c, si * tg);
      float tc = 1.f - 2.f / (1.f + __expf(2.f * c));
      float h = so * tc;
      hph[tid] = (_Float16)h;
      outbuf[((size_t)b * T_ + t) * 200 + dir * H_ + tid] = (t < sl) ? (u16)f2b(h) : (u16)0;
    }
    __syncthreads();
    xc = xn; xn = xn2;
  }
}

// ---------------- CRF with LDS ring staging (r15 winner, unchanged) --------
__global__ __launch_bounds__(64) void crf_k(
    const float* __restrict__ f, const float* __restrict__ g,
    float* __restrict__ alpha, float* __restrict__ beta)
{
  int wg = blockIdx.x;
  int lane = threadIdx.x;
  __shared__ __align__(16) float gl[4][400];   // ring: row r -> slot r&3
  __shared__ __align__(16) float aw[20];       // alpha: a[t-1]; beta: f[t+1]+b[t+1]
  bool stv = lane < 50;
  int p0 = 8 * lane;                           // this lane stages floats [p0,p0+8)
  float4 rA0, rA1, rB0, rB1;                   // in-flight staged row (reg ring)

  if (wg < B_) {
    // ---------------- alpha ----------------
    int b = wg;
    const float* fp = f + (size_t)b * T_ * C_;
    const float* gp = g + (size_t)b * T_ * C_ * C_;
    float* ap = alpha + (size_t)b * T_ * C_;
    if (lane < C_) {
      float a0 = fp[lane];
      ap[lane] = a0;
      aw[lane] = a0;
    }
    if (stv) {
      float4 v0 = *(const float4*)(gp + 400 + p0);
      float4 v1 = *(const float4*)(gp + 404 + p0);
      *(float4*)&gl[1 & 3][p0] = v0;  *(float4*)&gl[1 & 3][p0 + 4] = v1;
      v0 = *(const float4*)(gp + 800 + p0);
      v1 = *(const float4*)(gp + 804 + p0);
      *(float4*)&gl[2 & 3][p0] = v0;  *(float4*)&gl[2 & 3][p0 + 4] = v1;
      rA0 = *(const float4*)(gp + 1200 + p0);       // row 3 in flight
      rA1 = *(const float4*)(gp + 1204 + p0);
    }
    for (int t = 1; t < T_; ++t) {
      if (stv && (t + 3 < T_)) {                    // issue loads for row t+3
        rB0 = *(const float4*)(gp + (size_t)(t + 3) * 400 + p0);
        rB1 = *(const float4*)(gp + (size_t)(t + 3) * 400 + p0 + 4);
      }
      if (lane < C_) {
        const float* gr = &gl[t & 3][0];
        float ft = fp[(size_t)t * C_ + lane];       // issued early, used late
        float awv[20];
        #pragma unroll
        for (int q = 0; q < 5; ++q)
          *(f32x4v*)&awv[4 * q] = ((const f32x4v*)aw)[q];   // uniform b128
        float s[20];
        #pragma unroll
        for (int i = 0; i < 20; ++i)
          s[i] = awv[i] + gr[i * 20 + lane];        // consecutive -> no conflict
        float m4[5];
        #pragma unroll
        for (int q = 0; q < 5; ++q)
          m4[q] = fmaxf(fmaxf(s[4*q], s[4*q+1]), fmaxf(s[4*q+2], s[4*q+3]));
        float m = fmaxf(fmaxf(m4[0], m4[1]), fmaxf(fmaxf(m4[2], m4[3]), m4[4]));
        float e4[5];
        #pragma unroll
        for (int q = 0; q < 5; ++q) {
          float e0 = __expf(s[4*q] - m),   e1 = __expf(s[4*q+1] - m);
          float e2 = __expf(s[4*q+2] - m), e3 = __expf(s[4*q+3] - m);
          e4[q] = (e0 + e1) + (e2 + e3);
        }
        float sum = (e4[0] + e4[1]) + ((e4[2] + e4[3]) + e4[4]);
        float an = ft + m + __logf(sum);
        ap[(size_t)t * C_ + lane] = an;
        aw[lane] = an;
      }
      if (stv && (t + 2 < T_)) {                    // write row t+2 (loaded last step)
        *(float4*)&gl[(t + 2) & 3][p0] = rA0;
        *(float4*)&gl[(t + 2) & 3][p0 + 4] = rA1;
      }
      rA0 = rB0; rA1 = rB1;
    }
  } else {
    // ---------------- beta ----------------
    int b = wg - B_;
    const float* fp = f + (size_t)b * T_ * C_;
    const float* gp = g + (size_t)b * T_ * C_ * C_;
    float* bp = beta + (size_t)b * T_ * C_;
    if (lane < C_) {
      bp[(size_t)(T_ - 1) * C_ + lane] = 0.f;
      aw[lane] = fp[(size_t)(T_ - 1) * C_ + lane];  // w = f[T-1] + 0
    }
    if (stv) {
      float4 v0 = *(const float4*)(gp + (size_t)(T_ - 1) * 400 + p0);
      float4 v1 = *(const float4*)(gp + (size_t)(T_ - 1) * 400 + p0 + 4);
      *(float4*)&gl[(T_ - 1) & 3][p0] = v0;  *(float4*)&gl[(T_ - 1) & 3][p0 + 4] = v1;
      v0 = *(const float4*)(gp + (size_t)(T_ - 2) * 400 + p0);
      v1 = *(const float4*)(gp + (size_t)(T_ - 2) * 400 + p0 + 4);
      *(float4*)&gl[(T_ - 2) & 3][p0] = v0;  *(float4*)&gl[(T_ - 2) & 3][p0 + 4] = v1;
      rA0 = *(const float4*)(gp + (size_t)(T_ - 3) * 400 + p0);   // row T-3 in flight
      rA1 = *(const float4*)(gp + (size_t)(T_ - 3) * 400 + p0 + 4);
    }
    for (int u = 1; u < T_; ++u) {
      int t = T_ - 1 - u;          // computing beta[t]
      int r = t + 1;               // uses g row r
      if (stv && (r - 3 >= 1)) {   // issue loads for row r-3
        rB0 = *(const float4*)(gp + (size_t)(r - 3) * 400 + p0);
        rB1 = *(const float4*)(gp + (size_t)(r - 3) * 400 + p0 + 4);
      }
      if (lane < C_) {
        const float* gr = &gl[r & 3][lane * 20];
        float fcur = fp[(size_t)t * C_ + lane];
        float awv[20];
        #pragma unroll
        for (int q = 0; q < 5; ++q)
          *(f32x4v*)&awv[4 * q] = ((const f32x4v*)aw)[q];
        float s[20];
        #pragma unroll
        for (int q = 0; q < 5; ++q) {
          f32x4v gq = *(const f32x4v*)&gr[4 * q];   // per-lane b128, stride 80B
          s[4*q]   = awv[4*q]   + gq[0];
          s[4*q+1] = awv[4*q+1] + gq[1];
          s[4*q+2] = awv[4*q+2] + gq[2];
          s[4*q+3] = awv[4*q+3] + gq[3];
        }
        float m4[5];
        #pragma unroll
        for (int q = 0; q < 5; ++q)
          m4[q] = fmaxf(fmaxf(s[4*q], s[4*q+1]), fmaxf(s[4*q+2], s[4*q+3]));
        float m = fmaxf(fmaxf(m4[0], m4[1]), fmaxf(fmaxf(m4[2], m4[3]), m4[4]));
        float e4[5];
        #pragma unroll
        for (int q = 0; q < 5; ++q) {
          float e0 = __expf(s[4*q] - m),   e1 = __expf(s[4*q+1] - m);
          float e2 = __expf(s[4*q+2] - m), e3 = __expf(s[4*q+3] - m);
          e4[q] = (e0 + e1) + (e2 + e3);
        }
        float sum = (e4[0] + e4[1]) + ((e4[2] + e4[3]) + e4[4]);
        float bn = m + __logf(sum);
        bp[(size_t)t * C_ + lane] = bn;
        aw[lane] = fcur + bn;      // w for next step
      }
      if (stv && (r - 2 >= 1)) {   // write row r-2 (loaded last step)
        *(float4*)&gl[(r - 2) & 3][p0] = rA0;
        *(float4*)&gl[(r - 2) & 3][p0 + 4] = rA1;
      }
      rA0 = rB0; rA1 = rB1;
    }
  }
}

// ---------------- logZ per batch ----------------
__global__ void logz_k(const float* __restrict__ alpha, float* __restrict__ lz) {
  int b = blockIdx.x; int lane = threadIdx.x;
  float a = (lane < C_) ? alpha[((size_t)b * T_ + (T_ - 1)) * C_ + lane] : -3.0e38f;
  float m = a;
  #pragma unroll
  for (int o = 32; o > 0; o >>= 1) m = fmaxf(m, __shfl_xor(m, o));
  float e = (lane < C_) ? __expf(a - m) : 0.f;
  #pragma unroll
  for (int o = 32; o > 0; o >>= 1) e += __shfl_xor(e, o);
  if (lane == 0) lz[b] = m + __logf(e);
}

// ---------------- marginals = exp(alpha+beta-logZ) ----------------
__global__ void marg_k(const float* __restrict__ alpha, const float* __restrict__ beta,
                       const float* __restrict__ lz, float* __restrict__ out0) {
  size_t idx = (size_t)blockIdx.x * 256 + threadIdx.x;
  int b = (int)(idx / (T_ * C_));
  out0[idx] = __expf(alpha[idx] + beta[idx] - lz[b]);
}

extern "C" void kernel_launch(void* const* d_in, const int* in_sizes, int n_in,
                              void* d_out, int out_size, void* d_ws, size_t ws_size,
                              hipStream_t stream) {
  const int*   tok   = (const int*)d_in[0];
  const int*   seq   = (const int*)d_in[1];
  const float* emb   = (const float*)d_in[2];
  const float* Wih0  = (const float*)d_in[3];
  const float* Whh0  = (const float*)d_in[4];
  const float* bih0  = (const float*)d_in[5];
  const float* bhh0  = (const float*)d_in[6];
  const float* Wih0r = (const float*)d_in[7];
  const float* Whh0r = (const float*)d_in[8];
  const float* bih0r = (const float*)d_in[9];
  const float* bhh0r = (const float*)d_in[10];
  const float* Wih1  = (const float*)d_in[11];
  const float* Whh1  = (const float*)d_in[12];
  const float* bih1  = (const float*)d_in[13];
  const float* bhh1  = (const float*)d_in[14];
  const float* Wih1r = (const float*)d_in[15];
  const float* Whh1r = (const float*)d_in[16];
  const float* bih1r = (const float*)d_in[17];
  const float* bhh1r = (const float*)d_in[18];
  const float* fW    = (const float*)d_in[19];
  const float* fb    = (const float*)d_in[20];
  const float* gW    = (const float*)d_in[21];
  const float* gb    = (const float*)d_in[22];
  const float* h0    = (const float*)d_in[23];
  const float* c0    = (const float*)d_in[24];

  float* ws = (float*)d_ws;
  float* x0  = ws;                          // 4,194,304 floats
  u16*   xp  = (u16*)(ws + 4194304);        // 104,857,600 bf16
  u16*   x1  = (u16*)(ws + 109051904);      // 26,214,400 bf16
  float* lz  = ws + 135266304;              // 128 floats

  float* out   = (float*)d_out;
  float* f_out = out + 2621440;
  float* g_out = out + 5242880;
  float* a_out = out + 57671680;
  float* b_out = out + 60293120;

  embed_k<<<16384, 256, 0, stream>>>(tok, emb, x0);

  dim3 g400(2048, 7), g20(2048, 1);
  // layer 0 input projections (K=32): fp32 A -> bf16 xp
  gemm_mfma_t<0,1><<<g400, 256, 0, stream>>>(x0, Wih0,  bih0,  bhh0,  xp,                    32, 400, 400);
  gemm_mfma_t<0,1><<<g400, 256, 0, stream>>>(x0, Wih0r, bih0r, bhh0r, xp + (size_t)52428800, 32, 400, 400);
  lstm_scan<<<256, 512, 0, stream>>>(xp, Whh0, Whh0r, h0, c0, nullptr, x1, 0);
  // layer 1 input projections (K=200): bf16 A -> bf16 xp
  gemm_mfma_t<1,1><<<g400, 256, 0, stream>>>(x1, Wih1,  bih1,  bhh1,  xp,                    200, 400, 400);
  gemm_mfma_t<1,1><<<g400, 256, 0, stream>>>(x1, Wih1r, bih1r, bhh1r, xp + (size_t)52428800, 200, 400, 400);
  lstm_scan<<<256, 512, 0, stream>>>(xp, Whh1, Whh1r, h0, c0, seq, x1, 1);
  // emissions + transitions: bf16 A -> fp32 outputs
  gemm_mfma_t<1,0><<<g20,  256, 0, stream>>>(x1, fW, fb, nullptr, f_out, 200, 20,  20);
  gemm_mfma_t<1,0><<<g400, 256, 0, stream>>>(x1, gW, gb, nullptr, g_out, 200, 400, 400);
  // CRF forward/backward
  crf_k<<<256, 64, 0, stream>>>(f_out, g_out, a_out, b_out);
  logz_k<<<128, 64, 0, stream>>>(a_out, lz);
  marg_k<<<10240, 256, 0, stream>>>(a_out, b_out, lz, out);
}